// Round 1
// baseline (4483.496 us; speedup 1.0000x reference)
//
#include <hip/hip_runtime.h>
#include <hip/hip_bf16.h>

#define N_NODES 50000
#define N_EDGES 800000
#define ET_EDGES 850000   // + self loops
#define HEADS 4

__device__ __forceinline__ float lrelu(float v) { return v > 0.f ? v : 0.2f * v; }

__device__ __forceinline__ void atomicMaxFloat(float* addr, float value) {
    if (value >= 0.f) {
        atomicMax((int*)addr, __float_as_int(value));
    } else {
        atomicMin((unsigned int*)addr, __float_as_uint(value));
    }
}

// ---------------- encoder: x[7] -> relu(w1) -> w2 -> h[64] ----------------
__global__ __launch_bounds__(64) void encoder_kernel(
    const float* __restrict__ x, const float* __restrict__ w1, const float* __restrict__ b1,
    const float* __restrict__ w2, const float* __restrict__ b2, float* __restrict__ out) {
    int n = blockIdx.x;
    int c = threadIdx.x;
    __shared__ float s_t[64];
    float acc = b1[c];
    #pragma unroll
    for (int k = 0; k < 7; ++k) acc += x[n * 7 + k] * w1[k * 64 + c];
    s_t[c] = fmaxf(acc, 0.f);
    __syncthreads();
    float acc2 = b2[c];
    #pragma unroll 8
    for (int k = 0; k < 64; ++k) acc2 += s_t[k] * w2[k * 64 + c];
    out[n * 64 + c] = acc2;
}

// ---------------- GAT1 transform: h[64] @ W[64,256] -> h1[256] ----------------
__global__ __launch_bounds__(256) void gat1_transform(
    const float* __restrict__ hin, const float* __restrict__ W, float* __restrict__ hout) {
    __shared__ float s_h[8][64];
    int node0 = blockIdx.x * 8;
    int tid = threadIdx.x;
    for (int i = tid; i < 8 * 64; i += 256) {
        int m = i >> 6, k = i & 63;
        s_h[m][k] = hin[(node0 + m) * 64 + k];
    }
    __syncthreads();
    float acc[8] = {0.f, 0.f, 0.f, 0.f, 0.f, 0.f, 0.f, 0.f};
    for (int k = 0; k < 64; ++k) {
        float w = W[k * 256 + tid];
        #pragma unroll
        for (int m = 0; m < 8; ++m) acc[m] += s_h[m][k] * w;
    }
    #pragma unroll
    for (int m = 0; m < 8; ++m) hout[(node0 + m) * 256 + tid] = acc[m];
}

// ---------------- GAT2 transform: elu(out1 + b)[256] @ W[256,64] -> h2[64] ----------------
__global__ __launch_bounds__(64) void gat2_transform(
    const float* __restrict__ hin, const float* __restrict__ bias,
    const float* __restrict__ W, float* __restrict__ hout) {
    __shared__ float s_h[16][256];
    int node0 = blockIdx.x * 16;
    int tid = threadIdx.x;
    for (int i = tid; i < 16 * 256; i += 64) {
        int m = i >> 8, k = i & 255;
        float v = hin[(node0 + m) * 256 + k] + bias[k];
        s_h[m][k] = v > 0.f ? v : expm1f(v);   // ELU
    }
    __syncthreads();
    float acc[16];
    #pragma unroll
    for (int m = 0; m < 16; ++m) acc[m] = 0.f;
    for (int k = 0; k < 256; ++k) {
        float w = W[k * 64 + tid];
        #pragma unroll
        for (int m = 0; m < 16; ++m) acc[m] += s_h[m][k] * w;
    }
    #pragma unroll
    for (int m = 0; m < 16; ++m) hout[(node0 + m) * 64 + tid] = acc[m];
}

// ---------------- per-(node,head) attention scalars ----------------
template <int C>
__global__ __launch_bounds__(256) void alpha_kernel(
    const float* __restrict__ h, const float* __restrict__ a_src, const float* __restrict__ a_dst,
    float* __restrict__ as_out, float* __restrict__ ad_out) {
    int idx = blockIdx.x * 256 + threadIdx.x;   // over N*4*C exactly
    int k = idx % C;
    int g = idx / C;
    int hd = g % HEADS;
    int n = g / HEADS;
    if (n >= N_NODES) return;
    float v = h[n * (HEADS * C) + hd * C + k];
    float vs = v * a_src[hd * C + k];
    float vd = v * a_dst[hd * C + k];
    #pragma unroll
    for (int off = C / 2; off > 0; off >>= 1) {
        vs += __shfl_xor(vs, off);
        vd += __shfl_xor(vd, off);
    }
    if (k == 0) {
        as_out[n * HEADS + hd] = vs;
        ad_out[n * HEADS + hd] = vd;
    }
}

__device__ __forceinline__ void edge_sd(const int* __restrict__ ei, int e, int& s, int& d) {
    if (e < N_EDGES) { s = ei[e]; d = ei[N_EDGES + e]; }
    else { s = d = e - N_EDGES; }
}

// ---------------- pass A: logits + segment max ----------------
__global__ __launch_bounds__(256) void edge_logits_kernel(
    const int* __restrict__ ei, const float* __restrict__ as, const float* __restrict__ ad,
    float* __restrict__ ebuf, float* __restrict__ m) {
    int e = blockIdx.x * 256 + threadIdx.x;
    if (e >= ET_EDGES) return;
    int s, d;
    edge_sd(ei, e, s, d);
    float4 a = *(const float4*)(as + s * 4);
    float4 b = *(const float4*)(ad + d * 4);
    float4 ev;
    ev.x = lrelu(a.x + b.x);
    ev.y = lrelu(a.y + b.y);
    ev.z = lrelu(a.z + b.z);
    ev.w = lrelu(a.w + b.w);
    *(float4*)(ebuf + e * 4) = ev;
    atomicMaxFloat(m + d * 4 + 0, ev.x);
    atomicMaxFloat(m + d * 4 + 1, ev.y);
    atomicMaxFloat(m + d * 4 + 2, ev.z);
    atomicMaxFloat(m + d * 4 + 3, ev.w);
}

// ---------------- pass B: exp + segment sum ----------------
__global__ __launch_bounds__(256) void edge_exp_kernel(
    const int* __restrict__ ei, float* __restrict__ ebuf,
    const float* __restrict__ m, float* __restrict__ den) {
    int e = blockIdx.x * 256 + threadIdx.x;
    if (e >= ET_EDGES) return;
    int s, d;
    edge_sd(ei, e, s, d);
    float4 p = *(float4*)(ebuf + e * 4);
    float4 mm = *(const float4*)(m + d * 4);
    p.x = __expf(p.x - mm.x);
    p.y = __expf(p.y - mm.y);
    p.z = __expf(p.z - mm.z);
    p.w = __expf(p.w - mm.w);
    *(float4*)(ebuf + e * 4) = p;
    atomicAdd(den + d * 4 + 0, p.x);
    atomicAdd(den + d * 4 + 1, p.y);
    atomicAdd(den + d * 4 + 2, p.z);
    atomicAdd(den + d * 4 + 3, p.w);
}

// ---------------- pass C: weighted scatter-aggregate ----------------
template <int C>   // per-head channels; row = 4*C floats
__global__ __launch_bounds__(256) void aggregate_kernel(
    const int* __restrict__ ei, const float* __restrict__ hfeat,
    const float* __restrict__ ebuf, const float* __restrict__ den, float* __restrict__ out) {
    constexpr int TOT = 4 * C;
    int idx = blockIdx.x * 256 + threadIdx.x;   // over ET*C exactly
    int edge = idx / C;
    if (edge >= ET_EDGES) return;
    int chunk = idx % C;
    int c4 = chunk * 4;
    int head = c4 / C;
    int s, d;
    edge_sd(ei, edge, s, d);
    float alpha = ebuf[edge * 4 + head] / (den[d * 4 + head] + 1e-16f);
    float4 v = *(const float4*)(hfeat + (size_t)s * TOT + c4);
    float* o = out + (size_t)d * TOT + c4;
    atomicAdd(o + 0, v.x * alpha);
    atomicAdd(o + 1, v.y * alpha);
    atomicAdd(o + 2, v.z * alpha);
    atomicAdd(o + 3, v.w * alpha);
}

// ---------------- decoder: (out2 + g2_b)[64] -> relu(w1) -> w2 -> out[4] ----------------
__global__ __launch_bounds__(64) void decoder_kernel(
    const float* __restrict__ hin, const float* __restrict__ gb,
    const float* __restrict__ w1, const float* __restrict__ b1,
    const float* __restrict__ w2, const float* __restrict__ b2, float* __restrict__ out) {
    int n = blockIdx.x;
    int c = threadIdx.x;
    __shared__ float s_h[64];
    __shared__ float s_t[64];
    s_h[c] = hin[n * 64 + c] + gb[c];
    __syncthreads();
    float acc = b1[c];
    #pragma unroll 8
    for (int k = 0; k < 64; ++k) acc += s_h[k] * w1[k * 64 + c];
    s_t[c] = fmaxf(acc, 0.f);
    __syncthreads();
    if (c < 4) {
        float acc2 = b2[c];
        #pragma unroll 8
        for (int k = 0; k < 64; ++k) acc2 += s_t[k] * w2[k * 4 + c];
        out[n * 4 + c] = acc2;
    }
}

extern "C" void kernel_launch(void* const* d_in, const int* in_sizes, int n_in,
                              void* d_out, int out_size, void* d_ws, size_t ws_size,
                              hipStream_t stream) {
    const float* x      = (const float*)d_in[0];
    const int*   ei     = (const int*)d_in[1];
    const float* enc_w1 = (const float*)d_in[2];
    const float* enc_b1 = (const float*)d_in[3];
    const float* enc_w2 = (const float*)d_in[4];
    const float* enc_b2 = (const float*)d_in[5];
    const float* g1_w   = (const float*)d_in[6];
    const float* g1_as  = (const float*)d_in[7];
    const float* g1_ad  = (const float*)d_in[8];
    const float* g1_b   = (const float*)d_in[9];
    const float* g2_w   = (const float*)d_in[10];
    const float* g2_as  = (const float*)d_in[11];
    const float* g2_ad  = (const float*)d_in[12];
    const float* g2_b   = (const float*)d_in[13];
    const float* dec_w1 = (const float*)d_in[14];
    const float* dec_b1 = (const float*)d_in[15];
    const float* dec_w2 = (const float*)d_in[16];
    const float* dec_b2 = (const float*)d_in[17];

    const int N = N_NODES, ET = ET_EDGES;

    // workspace layout (floats)
    float* ws   = (float*)d_ws;
    float* h1   = ws;                       // 12,800,000  (reused later as out2)
    float* out1 = ws + 12800000;            // 12,800,000
    float* henc = ws + 25600000;            //  3,200,000  (reused later as h2)
    float* ebuf = ws + 28800000;            //  3,400,000
    float* m1   = ws + 32200000;            //    200,000
    float* m2   = m1 + 200000;
    float* den1 = m2 + 200000;
    float* den2 = den1 + 200000;
    float* as1  = den2 + 200000;
    float* ad1  = as1 + 200000;
    float* as2  = ad1 + 200000;
    float* ad2  = as2 + 200000;
    float* h2   = henc;   // overlay: h_enc dead after gat1_transform
    float* out2 = h1;     // overlay: h1 dead after aggregate<64>; memset mid-stream

    // init (ws is poisoned with 0xAA before every call)
    hipMemsetAsync(out1, 0, (size_t)N * 256 * sizeof(float), stream);
    hipMemsetAsync(m1, 0xFF, (size_t)N * 4 * sizeof(float) * 2, stream);  // m1+m2 -> -NaN sentinel
    hipMemsetAsync(den1, 0, (size_t)N * 4 * sizeof(float) * 2, stream);   // den1+den2

    encoder_kernel<<<N, 64, 0, stream>>>(x, enc_w1, enc_b1, enc_w2, enc_b2, henc);
    gat1_transform<<<N / 8, 256, 0, stream>>>(henc, g1_w, h1);
    alpha_kernel<64><<<N * 4 * 64 / 256, 256, 0, stream>>>(h1, g1_as, g1_ad, as1, ad1);
    edge_logits_kernel<<<(ET + 255) / 256, 256, 0, stream>>>(ei, as1, ad1, ebuf, m1);
    edge_exp_kernel<<<(ET + 255) / 256, 256, 0, stream>>>(ei, ebuf, m1, den1);
    aggregate_kernel<64><<<(ET * 64) / 256, 256, 0, stream>>>(ei, h1, ebuf, den1, out1);

    hipMemsetAsync(out2, 0, (size_t)N * 64 * sizeof(float), stream);  // after h1 is dead
    gat2_transform<<<N / 16, 64, 0, stream>>>(out1, g1_b, g2_w, h2);
    alpha_kernel<16><<<N * 4 * 16 / 256, 256, 0, stream>>>(h2, g2_as, g2_ad, as2, ad2);
    edge_logits_kernel<<<(ET + 255) / 256, 256, 0, stream>>>(ei, as2, ad2, ebuf, m2);
    edge_exp_kernel<<<(ET + 255) / 256, 256, 0, stream>>>(ei, ebuf, m2, den2);
    aggregate_kernel<16><<<(ET * 16) / 256, 256, 0, stream>>>(ei, h2, ebuf, den2, out2);

    decoder_kernel<<<N, 64, 0, stream>>>(out2, g2_b, dec_w1, dec_b1, dec_w2, dec_b2, (float*)d_out);
}

// Round 2
// 694.531 us; speedup vs baseline: 6.4554x; 6.4554x over previous
//
#include <hip/hip_runtime.h>
#include <hip/hip_bf16.h>

#define N_NODES 50000
#define N_EDGES 800000
#define ET_EDGES 850000   // + self loops
#define HEADS 4

__device__ __forceinline__ float lrelu(float v) { return v > 0.f ? v : 0.2f * v; }

__device__ __forceinline__ void edge_sd(const int* __restrict__ ei, int e, int& s, int& d) {
    if (e < N_EDGES) { s = ei[e]; d = ei[N_EDGES + e]; }
    else { s = d = e - N_EDGES; }
}

// ---------------- CSR build ----------------
__global__ __launch_bounds__(256) void count_kernel(const int* __restrict__ ei, int* __restrict__ deg) {
    int e = blockIdx.x * 256 + threadIdx.x;
    if (e >= ET_EDGES) return;
    int s, d; edge_sd(ei, e, s, d);
    atomicAdd(deg + d, 1);
}

__global__ __launch_bounds__(1024) void scan_kernel(const int* __restrict__ deg,
                                                    int* __restrict__ row, int* __restrict__ cursor) {
    __shared__ int s[1024];
    __shared__ int s_carry;
    int tid = threadIdx.x;
    if (tid == 0) s_carry = 0;
    __syncthreads();
    for (int base = 0; base < N_NODES; base += 1024) {
        int i = base + tid;
        int v = (i < N_NODES) ? deg[i] : 0;
        s[tid] = v;
        __syncthreads();
        for (int off = 1; off < 1024; off <<= 1) {
            int t = (tid >= off) ? s[tid - off] : 0;
            __syncthreads();
            s[tid] += t;
            __syncthreads();
        }
        int incl = s[tid] + s_carry;
        int excl = incl - v;
        if (i < N_NODES) { row[i] = excl; cursor[i] = excl; }
        __syncthreads();
        if (tid == 1023) s_carry = incl;
        __syncthreads();
    }
    if (tid == 0) row[N_NODES] = s_carry;
}

__global__ __launch_bounds__(256) void scatter_kernel(const int* __restrict__ ei,
                                                      int* __restrict__ cursor, int* __restrict__ csr_src) {
    int e = blockIdx.x * 256 + threadIdx.x;
    if (e >= ET_EDGES) return;
    int s, d; edge_sd(ei, e, s, d);
    int pos = atomicAdd(cursor + d, 1);
    csr_src[pos] = s;
}

// ---------------- encoder: x[7] -> relu(w1) -> w2 -> h[64] ----------------
__global__ __launch_bounds__(64) void encoder_kernel(
    const float* __restrict__ x, const float* __restrict__ w1, const float* __restrict__ b1,
    const float* __restrict__ w2, const float* __restrict__ b2, float* __restrict__ out) {
    int n = blockIdx.x;
    int c = threadIdx.x;
    __shared__ float s_t[64];
    float acc = b1[c];
    #pragma unroll
    for (int k = 0; k < 7; ++k) acc += x[n * 7 + k] * w1[k * 64 + c];
    s_t[c] = fmaxf(acc, 0.f);
    __syncthreads();
    float acc2 = b2[c];
    #pragma unroll 8
    for (int k = 0; k < 64; ++k) acc2 += s_t[k] * w2[k * 64 + c];
    out[n * 64 + c] = acc2;
}

// ---------------- GAT1 transform: h[64] @ W[64,256] -> h1[256] ----------------
__global__ __launch_bounds__(256) void gat1_transform(
    const float* __restrict__ hin, const float* __restrict__ W, float* __restrict__ hout) {
    __shared__ float s_h[8][64];
    int node0 = blockIdx.x * 8;
    int tid = threadIdx.x;
    for (int i = tid; i < 8 * 64; i += 256) {
        int m = i >> 6, k = i & 63;
        s_h[m][k] = hin[(node0 + m) * 64 + k];
    }
    __syncthreads();
    float acc[8] = {0.f, 0.f, 0.f, 0.f, 0.f, 0.f, 0.f, 0.f};
    for (int k = 0; k < 64; ++k) {
        float w = W[k * 256 + tid];
        #pragma unroll
        for (int m = 0; m < 8; ++m) acc[m] += s_h[m][k] * w;
    }
    #pragma unroll
    for (int m = 0; m < 8; ++m) hout[(node0 + m) * 256 + tid] = acc[m];
}

// ---------------- GAT2 transform: elu(out1 + b)[256] @ W[256,64] -> h2[64] ----------------
__global__ __launch_bounds__(64) void gat2_transform(
    const float* __restrict__ hin, const float* __restrict__ bias,
    const float* __restrict__ W, float* __restrict__ hout) {
    __shared__ float s_h[16][256];
    int node0 = blockIdx.x * 16;
    int tid = threadIdx.x;
    for (int i = tid; i < 16 * 256; i += 64) {
        int m = i >> 8, k = i & 255;
        float v = hin[(node0 + m) * 256 + k] + bias[k];
        s_h[m][k] = v > 0.f ? v : expm1f(v);   // ELU
    }
    __syncthreads();
    float acc[16];
    #pragma unroll
    for (int m = 0; m < 16; ++m) acc[m] = 0.f;
    for (int k = 0; k < 256; ++k) {
        float w = W[k * 64 + tid];
        #pragma unroll
        for (int m = 0; m < 16; ++m) acc[m] += s_h[m][k] * w;
    }
    #pragma unroll
    for (int m = 0; m < 16; ++m) hout[(node0 + m) * 64 + tid] = acc[m];
}

// ---------------- per-(node,head) attention scalars ----------------
template <int C>
__global__ __launch_bounds__(256) void alpha_kernel(
    const float* __restrict__ h, const float* __restrict__ a_src, const float* __restrict__ a_dst,
    float* __restrict__ as_out, float* __restrict__ ad_out) {
    int idx = blockIdx.x * 256 + threadIdx.x;   // over N*4*C exactly
    int k = idx % C;
    int g = idx / C;
    int hd = g % HEADS;
    int n = g / HEADS;
    if (n >= N_NODES) return;
    float v = h[n * (HEADS * C) + hd * C + k];
    float vs = v * a_src[hd * C + k];
    float vd = v * a_dst[hd * C + k];
    #pragma unroll
    for (int off = C / 2; off > 0; off >>= 1) {
        vs += __shfl_xor(vs, off);
        vd += __shfl_xor(vd, off);
    }
    if (k == 0) {
        as_out[n * HEADS + hd] = vs;
        ad_out[n * HEADS + hd] = vd;
    }
}

// ---------------- dst-centric fused softmax + aggregate: one wave per node ----------------
template <int C>   // per-head channels; row = 4*C floats; VEC = 4*C/64 floats per lane
__global__ __launch_bounds__(256) void gat_aggregate(
    const int* __restrict__ row, const int* __restrict__ csr_src,
    const float* __restrict__ as, const float* __restrict__ ad,
    const float* __restrict__ h, float* __restrict__ out) {
    constexpr int TOT = 4 * C;
    constexpr int VEC = TOT / 64;
    int wslot = threadIdx.x >> 6;
    int lane  = threadIdx.x & 63;
    int n = blockIdx.x * 4 + wslot;
    __shared__ int   ls[4][64];
    __shared__ float lp[4][64 * 4];
    if (n >= N_NODES) return;
    int base = row[n];
    int deg  = row[n + 1] - base;
    int head = lane >> 4;          // == (lane*VEC)/C for both C=64 and C=16
    float4 add = *(const float4*)(ad + n * 4);

    // pass 1: per-head max over incoming edges (lane-parallel + butterfly)
    float4 m = make_float4(-1e30f, -1e30f, -1e30f, -1e30f);
    for (int c0 = 0; c0 < deg; c0 += 64) {
        int j = c0 + lane;
        float4 e = make_float4(-1e30f, -1e30f, -1e30f, -1e30f);
        if (j < deg) {
            int s = csr_src[base + j];
            float4 a = *(const float4*)(as + s * 4);
            e.x = lrelu(a.x + add.x); e.y = lrelu(a.y + add.y);
            e.z = lrelu(a.z + add.z); e.w = lrelu(a.w + add.w);
        }
        #pragma unroll
        for (int off = 32; off > 0; off >>= 1) {
            e.x = fmaxf(e.x, __shfl_xor(e.x, off));
            e.y = fmaxf(e.y, __shfl_xor(e.y, off));
            e.z = fmaxf(e.z, __shfl_xor(e.z, off));
            e.w = fmaxf(e.w, __shfl_xor(e.w, off));
        }
        m.x = fmaxf(m.x, e.x); m.y = fmaxf(m.y, e.y);
        m.z = fmaxf(m.z, e.z); m.w = fmaxf(m.w, e.w);
    }

    // pass 2: exp + denom sum + feature accumulate
    float4 l = make_float4(0.f, 0.f, 0.f, 0.f);
    float acc[VEC];
    #pragma unroll
    for (int q = 0; q < VEC; ++q) acc[q] = 0.f;
    for (int c0 = 0; c0 < deg; c0 += 64) {
        int j = c0 + lane;
        int s = 0;
        float4 p = make_float4(0.f, 0.f, 0.f, 0.f);
        if (j < deg) {
            s = csr_src[base + j];
            float4 a = *(const float4*)(as + s * 4);
            p.x = __expf(lrelu(a.x + add.x) - m.x);
            p.y = __expf(lrelu(a.y + add.y) - m.y);
            p.z = __expf(lrelu(a.z + add.z) - m.z);
            p.w = __expf(lrelu(a.w + add.w) - m.w);
        }
        ls[wslot][lane] = s;
        *(float4*)(&lp[wslot][lane * 4]) = p;
        float4 t = p;
        #pragma unroll
        for (int off = 32; off > 0; off >>= 1) {
            t.x += __shfl_xor(t.x, off);
            t.y += __shfl_xor(t.y, off);
            t.z += __shfl_xor(t.z, off);
            t.w += __shfl_xor(t.w, off);
        }
        l.x += t.x; l.y += t.y; l.z += t.z; l.w += t.w;
        int cnt = min(64, deg - c0);
        for (int j2 = 0; j2 < cnt; ++j2) {
            int sj = ls[wslot][j2];
            float pj = lp[wslot][j2 * 4 + head];
            const float* hp = h + (size_t)sj * TOT + lane * VEC;
            if (VEC == 4) {
                float4 v = *(const float4*)hp;
                acc[0] += pj * v.x;
                acc[1 % VEC] += pj * v.y;
                acc[2 % VEC] += pj * v.z;
                acc[3 % VEC] += pj * v.w;
            } else {
                acc[0] += pj * hp[0];
            }
        }
    }
    float lh = (head == 0) ? l.x : (head == 1) ? l.y : (head == 2) ? l.z : l.w;
    float inv = 1.f / (lh + 1e-16f);
    float* op = out + (size_t)n * TOT + lane * VEC;
    #pragma unroll
    for (int q = 0; q < VEC; ++q) op[q] = acc[q] * inv;
}

// ---------------- decoder: (out2 + g2_b)[64] -> relu(w1) -> w2 -> out[4] ----------------
__global__ __launch_bounds__(64) void decoder_kernel(
    const float* __restrict__ hin, const float* __restrict__ gb,
    const float* __restrict__ w1, const float* __restrict__ b1,
    const float* __restrict__ w2, const float* __restrict__ b2, float* __restrict__ out) {
    int n = blockIdx.x;
    int c = threadIdx.x;
    __shared__ float s_h[64];
    __shared__ float s_t[64];
    s_h[c] = hin[n * 64 + c] + gb[c];
    __syncthreads();
    float acc = b1[c];
    #pragma unroll 8
    for (int k = 0; k < 64; ++k) acc += s_h[k] * w1[k * 64 + c];
    s_t[c] = fmaxf(acc, 0.f);
    __syncthreads();
    if (c < 4) {
        float acc2 = b2[c];
        #pragma unroll 8
        for (int k = 0; k < 64; ++k) acc2 += s_t[k] * w2[k * 4 + c];
        out[n * 4 + c] = acc2;
    }
}

extern "C" void kernel_launch(void* const* d_in, const int* in_sizes, int n_in,
                              void* d_out, int out_size, void* d_ws, size_t ws_size,
                              hipStream_t stream) {
    const float* x      = (const float*)d_in[0];
    const int*   ei     = (const int*)d_in[1];
    const float* enc_w1 = (const float*)d_in[2];
    const float* enc_b1 = (const float*)d_in[3];
    const float* enc_w2 = (const float*)d_in[4];
    const float* enc_b2 = (const float*)d_in[5];
    const float* g1_w   = (const float*)d_in[6];
    const float* g1_as  = (const float*)d_in[7];
    const float* g1_ad  = (const float*)d_in[8];
    const float* g1_b   = (const float*)d_in[9];
    const float* g2_w   = (const float*)d_in[10];
    const float* g2_as  = (const float*)d_in[11];
    const float* g2_ad  = (const float*)d_in[12];
    const float* g2_b   = (const float*)d_in[13];
    const float* dec_w1 = (const float*)d_in[14];
    const float* dec_b1 = (const float*)d_in[15];
    const float* dec_w2 = (const float*)d_in[16];
    const float* dec_b2 = (const float*)d_in[17];

    const int N = N_NODES, ET = ET_EDGES;

    // workspace layout (floats)
    float* ws   = (float*)d_ws;
    float* h1   = ws;                       // 12,800,000 (reused later as out2)
    float* out1 = ws + 12800000;            // 12,800,000
    float* henc = ws + 25600000;            //  3,200,000 (reused later as h2)
    float* as1  = ws + 28800000;            //    200,000
    float* ad1  = as1 + 200000;
    float* as2  = ad1 + 200000;
    float* ad2  = as2 + 200000;
    int*   ib      = (int*)(ws + 29600000);
    int*   deg     = ib;                    // 50,001
    int*   rowp    = ib + 50004;            // 50,001
    int*   cursor  = ib + 100008;           // 50,001
    int*   csr_src = ib + 150012;           // 850,000
    float* h2   = henc;   // overlay
    float* out2 = h1;     // overlay: h1 dead after gat_aggregate<64>

    // CSR build (deg must be zeroed; ws is poisoned before every call)
    hipMemsetAsync(deg, 0, (size_t)(N + 1) * sizeof(int), stream);
    count_kernel<<<(ET + 255) / 256, 256, 0, stream>>>(ei, deg);
    scan_kernel<<<1, 1024, 0, stream>>>(deg, rowp, cursor);
    scatter_kernel<<<(ET + 255) / 256, 256, 0, stream>>>(ei, cursor, csr_src);

    encoder_kernel<<<N, 64, 0, stream>>>(x, enc_w1, enc_b1, enc_w2, enc_b2, henc);
    gat1_transform<<<N / 8, 256, 0, stream>>>(henc, g1_w, h1);
    alpha_kernel<64><<<N * 4 * 64 / 256, 256, 0, stream>>>(h1, g1_as, g1_ad, as1, ad1);
    gat_aggregate<64><<<(N + 3) / 4, 256, 0, stream>>>(rowp, csr_src, as1, ad1, h1, out1);

    gat2_transform<<<N / 16, 64, 0, stream>>>(out1, g1_b, g2_w, h2);
    alpha_kernel<16><<<N * 4 * 16 / 256, 256, 0, stream>>>(h2, g2_as, g2_ad, as2, ad2);
    gat_aggregate<16><<<(N + 3) / 4, 256, 0, stream>>>(rowp, csr_src, as2, ad2, h2, out2);

    decoder_kernel<<<N, 64, 0, stream>>>(out2, g2_b, dec_w1, dec_b1, dec_w2, dec_b2, (float*)d_out);
}

// Round 3
// 657.333 us; speedup vs baseline: 6.8207x; 1.0566x over previous
//
#include <hip/hip_runtime.h>
#include <hip/hip_bf16.h>

#define N_NODES 50000
#define N_EDGES 800000
#define ET_EDGES 850000   // + self loops
#define HEADS 4
#define NBLK 49           // ceil(N_NODES/1024)

__device__ __forceinline__ float lrelu(float v) { return v > 0.f ? v : 0.2f * v; }

__device__ __forceinline__ void edge_sd(const int* __restrict__ ei, int e, int& s, int& d) {
    if (e < N_EDGES) { s = ei[e]; d = ei[N_EDGES + e]; }
    else { s = d = e - N_EDGES; }
}

// ---------------- CSR build ----------------
__global__ __launch_bounds__(256) void count_kernel(const int* __restrict__ ei, int* __restrict__ deg) {
    int e = blockIdx.x * 256 + threadIdx.x;
    if (e >= ET_EDGES) return;
    int s, d; edge_sd(ei, e, s, d);
    atomicAdd(deg + d, 1);
}

// phase A: per-1024-block exclusive scan + block sums
__global__ __launch_bounds__(1024) void scanA_kernel(const int* __restrict__ deg,
                                                     int* __restrict__ rowp, int* __restrict__ bsum) {
    __shared__ int s[1024];
    int tid = threadIdx.x;
    int i = blockIdx.x * 1024 + tid;
    int v = (i < N_NODES) ? deg[i] : 0;
    s[tid] = v;
    __syncthreads();
    for (int off = 1; off < 1024; off <<= 1) {
        int t = (tid >= off) ? s[tid - off] : 0;
        __syncthreads();
        s[tid] += t;
        __syncthreads();
    }
    if (i < N_NODES) rowp[i] = s[tid] - v;          // exclusive within block
    if (tid == 1023) bsum[blockIdx.x] = s[1023];    // block total
}

// phase B: scan the 49 block sums (single wave)
__global__ __launch_bounds__(64) void scanB_kernel(const int* __restrict__ bsum,
                                                   int* __restrict__ boff, int* __restrict__ rowp) {
    int lane = threadIdx.x;
    int v = (lane < NBLK) ? bsum[lane] : 0;
    int x = v;
    #pragma unroll
    for (int off = 1; off < 64; off <<= 1) {
        int t = __shfl_up(x, off);
        if (lane >= off) x += t;
    }
    if (lane < NBLK) boff[lane] = x - v;            // exclusive
    if (lane == NBLK - 1) rowp[N_NODES] = x;        // grand total
}

// phase C: add block offsets, fill cursor
__global__ __launch_bounds__(256) void scanC_kernel(int* __restrict__ rowp,
                                                    const int* __restrict__ boff, int* __restrict__ cursor) {
    int i = blockIdx.x * 256 + threadIdx.x;
    if (i >= N_NODES) return;
    int v = rowp[i] + boff[i >> 10];
    rowp[i] = v;
    cursor[i] = v;
}

__global__ __launch_bounds__(256) void scatter_kernel(const int* __restrict__ ei,
                                                      int* __restrict__ cursor, int* __restrict__ csr_src) {
    int e = blockIdx.x * 256 + threadIdx.x;
    if (e >= ET_EDGES) return;
    int s, d; edge_sd(ei, e, s, d);
    int pos = atomicAdd(cursor + d, 1);
    csr_src[pos] = s;
}

// ---------------- fold attention vectors through g1_w: w~[h,k] = sum_c W[k,h*64+c]*a[h,c] ----------------
__global__ __launch_bounds__(256) void fold1_kernel(
    const float* __restrict__ g1w, const float* __restrict__ g1as, const float* __restrict__ g1ad,
    float* __restrict__ wsf, float* __restrict__ wdf) {
    int tid = threadIdx.x;       // tid = h*64+k
    int h = tid >> 6, k = tid & 63;
    float as_acc = 0.f, ad_acc = 0.f;
    #pragma unroll 8
    for (int c = 0; c < 64; ++c) {
        float w = g1w[k * 256 + h * 64 + c];
        as_acc += w * g1as[h * 64 + c];
        ad_acc += w * g1ad[h * 64 + c];
    }
    wsf[tid] = as_acc;
    wdf[tid] = ad_acc;
}

// ---------------- encoder: x[7] -> relu(w1) -> w2 -> henc[64], 8 nodes/block ----------------
__global__ __launch_bounds__(64) void encoder8_kernel(
    const float* __restrict__ x, const float* __restrict__ w1, const float* __restrict__ b1,
    const float* __restrict__ w2, const float* __restrict__ b2, float* __restrict__ henc) {
    int c = threadIdx.x;
    int node0 = blockIdx.x * 8;
    float w1c[7];
    #pragma unroll
    for (int k = 0; k < 7; ++k) w1c[k] = w1[k * 64 + c];
    float w2c[64];
    #pragma unroll
    for (int k = 0; k < 64; ++k) w2c[k] = w2[k * 64 + c];
    float b1c = b1[c], b2c = b2[c];
    __shared__ float s_x[8][8];
    for (int i = c; i < 56; i += 64) s_x[i / 7][i % 7] = x[node0 * 7 + i];
    __syncthreads();
    __shared__ float s_t[8][64];
    #pragma unroll
    for (int m = 0; m < 8; ++m) {
        float a = b1c;
        #pragma unroll
        for (int k = 0; k < 7; ++k) a += s_x[m][k] * w1c[k];
        s_t[m][c] = fmaxf(a, 0.f);
    }
    __syncthreads();
    #pragma unroll
    for (int m = 0; m < 8; ++m) {
        float a = b2c;
        #pragma unroll 16
        for (int k = 0; k < 64; ++k) a += s_t[m][k] * w2c[k];
        henc[(node0 + m) * 64 + c] = a;
    }
}

// ---------------- attention scalars from henc: as1[n,h] = henc[n]·wsf[h] ----------------
__global__ __launch_bounds__(256) void alpha1_kernel(
    const float* __restrict__ henc, const float* __restrict__ wsf, const float* __restrict__ wdf,
    float* __restrict__ as_out, float* __restrict__ ad_out) {
    int n = blockIdx.x;                 // one node per block, wave per head
    int r = threadIdx.x;
    int h = r >> 6, k = r & 63;
    float v = henc[n * 64 + k];
    float vs = v * wsf[h * 64 + k];
    float vd = v * wdf[h * 64 + k];
    #pragma unroll
    for (int off = 32; off > 0; off >>= 1) {
        vs += __shfl_xor(vs, off);
        vd += __shfl_xor(vd, off);
    }
    if (k == 0) {
        as_out[n * 4 + h] = vs;
        ad_out[n * 4 + h] = vd;
    }
}

// ---------------- GAT1 aggregation in henc-domain: agg[n][k*4+h] = sum_e alpha[e,h]*henc[src][k] ----------------
__global__ __launch_bounds__(256) void aggregate1_kernel(
    const int* __restrict__ row, const int* __restrict__ csr_src,
    const float* __restrict__ as, const float* __restrict__ ad,
    const float* __restrict__ henc, float* __restrict__ agg) {
    int wslot = threadIdx.x >> 6;
    int lane  = threadIdx.x & 63;
    int n = blockIdx.x * 4 + wslot;
    __shared__ int   ls[4][64];
    __shared__ float lp[4][256];
    if (n >= N_NODES) return;
    int base = row[n];
    int deg  = row[n + 1] - base;
    float4 add = *(const float4*)(ad + n * 4);

    // pass 1: per-head max
    float4 m = make_float4(-1e30f, -1e30f, -1e30f, -1e30f);
    for (int c0 = 0; c0 < deg; c0 += 64) {
        int j = c0 + lane;
        float4 e = make_float4(-1e30f, -1e30f, -1e30f, -1e30f);
        if (j < deg) {
            int s = csr_src[base + j];
            float4 a = *(const float4*)(as + s * 4);
            e.x = lrelu(a.x + add.x); e.y = lrelu(a.y + add.y);
            e.z = lrelu(a.z + add.z); e.w = lrelu(a.w + add.w);
        }
        #pragma unroll
        for (int off = 32; off > 0; off >>= 1) {
            e.x = fmaxf(e.x, __shfl_xor(e.x, off));
            e.y = fmaxf(e.y, __shfl_xor(e.y, off));
            e.z = fmaxf(e.z, __shfl_xor(e.z, off));
            e.w = fmaxf(e.w, __shfl_xor(e.w, off));
        }
        m.x = fmaxf(m.x, e.x); m.y = fmaxf(m.y, e.y);
        m.z = fmaxf(m.z, e.z); m.w = fmaxf(m.w, e.w);
    }

    // pass 2: exp + denom + accumulate henc (lane = channel k)
    float4 l = make_float4(0.f, 0.f, 0.f, 0.f);
    float4 acc = make_float4(0.f, 0.f, 0.f, 0.f);   // per-head accumulators
    for (int c0 = 0; c0 < deg; c0 += 64) {
        int j = c0 + lane;
        int s = 0;
        float4 p = make_float4(0.f, 0.f, 0.f, 0.f);
        if (j < deg) {
            s = csr_src[base + j];
            float4 a = *(const float4*)(as + s * 4);
            p.x = __expf(lrelu(a.x + add.x) - m.x);
            p.y = __expf(lrelu(a.y + add.y) - m.y);
            p.z = __expf(lrelu(a.z + add.z) - m.z);
            p.w = __expf(lrelu(a.w + add.w) - m.w);
        }
        ls[wslot][lane] = s;
        *(float4*)(&lp[wslot][lane * 4]) = p;
        float4 t = p;
        #pragma unroll
        for (int off = 32; off > 0; off >>= 1) {
            t.x += __shfl_xor(t.x, off);
            t.y += __shfl_xor(t.y, off);
            t.z += __shfl_xor(t.z, off);
            t.w += __shfl_xor(t.w, off);
        }
        l.x += t.x; l.y += t.y; l.z += t.z; l.w += t.w;
        int cnt = min(64, deg - c0);
        for (int j2 = 0; j2 < cnt; ++j2) {
            int sj = ls[wslot][j2];
            float4 pj = *(const float4*)(&lp[wslot][j2 * 4]);
            float v = henc[sj * 64 + lane];
            acc.x += pj.x * v; acc.y += pj.y * v;
            acc.z += pj.z * v; acc.w += pj.w * v;
        }
    }
    float4 r;
    r.x = acc.x / (l.x + 1e-16f);
    r.y = acc.y / (l.y + 1e-16f);
    r.z = acc.z / (l.z + 1e-16f);
    r.w = acc.w / (l.w + 1e-16f);
    *(float4*)(agg + (size_t)n * 256 + lane * 4) = r;
}

// ---------------- fused: out1 = agg @ W_h (+b1, ELU) ; h2 = elu(out1) @ g2_w. 8 nodes/block ----------------
__global__ __launch_bounds__(256) void gat1_finish_kernel(
    const float* __restrict__ agg, const float* __restrict__ g1w, const float* __restrict__ g1b,
    const float* __restrict__ g2w, float* __restrict__ h2) {
    int tid = threadIdx.x;
    int node0 = blockIdx.x * 8;
    __shared__ float s_agg[8][256];
    __shared__ float s_v[8][256];
    for (int i = tid; i < 8 * 256; i += 256)
        s_agg[i >> 8][i & 255] = agg[(size_t)node0 * 256 + i];
    __syncthreads();
    int h = tid >> 6;
    float accv[8] = {0.f, 0.f, 0.f, 0.f, 0.f, 0.f, 0.f, 0.f};
    for (int k = 0; k < 64; ++k) {
        float w = g1w[k * 256 + tid];
        #pragma unroll
        for (int m = 0; m < 8; ++m) accv[m] += s_agg[m][k * 4 + h] * w;
    }
    float bias = g1b[tid];
    #pragma unroll
    for (int m = 0; m < 8; ++m) {
        float v = accv[m] + bias;
        s_v[m][tid] = v > 0.f ? v : expm1f(v);   // ELU
    }
    __syncthreads();
    int m1 = tid >> 6;           // nodes m1 and m1+4
    int c2 = tid & 63;
    float a0 = 0.f, a1 = 0.f;
    for (int k = 0; k < 256; ++k) {
        float w = g2w[k * 64 + c2];
        a0 += s_v[m1][k] * w;
        a1 += s_v[m1 + 4][k] * w;
    }
    h2[(node0 + m1) * 64 + c2] = a0;
    h2[(node0 + m1 + 4) * 64 + c2] = a1;
}

// ---------------- per-(node,head) attention scalars for layer 2 ----------------
__global__ __launch_bounds__(256) void alpha2_kernel(
    const float* __restrict__ h, const float* __restrict__ a_src, const float* __restrict__ a_dst,
    float* __restrict__ as_out, float* __restrict__ ad_out) {
    int idx = blockIdx.x * 256 + threadIdx.x;   // over N*4*16 exactly
    int k = idx & 15;
    int g = idx >> 4;
    int hd = g & 3;
    int n = g >> 2;
    if (n >= N_NODES) return;
    float v = h[n * 64 + hd * 16 + k];
    float vs = v * a_src[hd * 16 + k];
    float vd = v * a_dst[hd * 16 + k];
    #pragma unroll
    for (int off = 8; off > 0; off >>= 1) {
        vs += __shfl_xor(vs, off);
        vd += __shfl_xor(vd, off);
    }
    if (k == 0) {
        as_out[n * 4 + hd] = vs;
        ad_out[n * 4 + hd] = vd;
    }
}

// ---------------- GAT2 dst-centric aggregate (post-transform, 64-float rows) ----------------
__global__ __launch_bounds__(256) void aggregate2_kernel(
    const int* __restrict__ row, const int* __restrict__ csr_src,
    const float* __restrict__ as, const float* __restrict__ ad,
    const float* __restrict__ h, float* __restrict__ out) {
    int wslot = threadIdx.x >> 6;
    int lane  = threadIdx.x & 63;
    int n = blockIdx.x * 4 + wslot;
    __shared__ int   ls[4][64];
    __shared__ float lp[4][256];
    if (n >= N_NODES) return;
    int base = row[n];
    int deg  = row[n + 1] - base;
    int head = lane >> 4;
    float4 add = *(const float4*)(ad + n * 4);

    float4 m = make_float4(-1e30f, -1e30f, -1e30f, -1e30f);
    for (int c0 = 0; c0 < deg; c0 += 64) {
        int j = c0 + lane;
        float4 e = make_float4(-1e30f, -1e30f, -1e30f, -1e30f);
        if (j < deg) {
            int s = csr_src[base + j];
            float4 a = *(const float4*)(as + s * 4);
            e.x = lrelu(a.x + add.x); e.y = lrelu(a.y + add.y);
            e.z = lrelu(a.z + add.z); e.w = lrelu(a.w + add.w);
        }
        #pragma unroll
        for (int off = 32; off > 0; off >>= 1) {
            e.x = fmaxf(e.x, __shfl_xor(e.x, off));
            e.y = fmaxf(e.y, __shfl_xor(e.y, off));
            e.z = fmaxf(e.z, __shfl_xor(e.z, off));
            e.w = fmaxf(e.w, __shfl_xor(e.w, off));
        }
        m.x = fmaxf(m.x, e.x); m.y = fmaxf(m.y, e.y);
        m.z = fmaxf(m.z, e.z); m.w = fmaxf(m.w, e.w);
    }

    float4 l = make_float4(0.f, 0.f, 0.f, 0.f);
    float acc = 0.f;
    for (int c0 = 0; c0 < deg; c0 += 64) {
        int j = c0 + lane;
        int s = 0;
        float4 p = make_float4(0.f, 0.f, 0.f, 0.f);
        if (j < deg) {
            s = csr_src[base + j];
            float4 a = *(const float4*)(as + s * 4);
            p.x = __expf(lrelu(a.x + add.x) - m.x);
            p.y = __expf(lrelu(a.y + add.y) - m.y);
            p.z = __expf(lrelu(a.z + add.z) - m.z);
            p.w = __expf(lrelu(a.w + add.w) - m.w);
        }
        ls[wslot][lane] = s;
        *(float4*)(&lp[wslot][lane * 4]) = p;
        float4 t = p;
        #pragma unroll
        for (int off = 32; off > 0; off >>= 1) {
            t.x += __shfl_xor(t.x, off);
            t.y += __shfl_xor(t.y, off);
            t.z += __shfl_xor(t.z, off);
            t.w += __shfl_xor(t.w, off);
        }
        l.x += t.x; l.y += t.y; l.z += t.z; l.w += t.w;
        int cnt = min(64, deg - c0);
        for (int j2 = 0; j2 < cnt; ++j2) {
            int sj = ls[wslot][j2];
            float pj = lp[wslot][j2 * 4 + head];
            acc += pj * h[sj * 64 + lane];
        }
    }
    float lh = (head == 0) ? l.x : (head == 1) ? l.y : (head == 2) ? l.z : l.w;
    out[(size_t)n * 64 + lane] = acc / (lh + 1e-16f);
}

// ---------------- decoder: (out2 + g2_b)[64] -> relu(w1) -> w2 -> out[4], 8 nodes/block ----------------
__global__ __launch_bounds__(64) void decoder8_kernel(
    const float* __restrict__ hin, const float* __restrict__ gb,
    const float* __restrict__ w1, const float* __restrict__ b1,
    const float* __restrict__ w2, const float* __restrict__ b2, float* __restrict__ out) {
    int c = threadIdx.x;
    int node0 = blockIdx.x * 8;
    float w1c[64];
    #pragma unroll
    for (int k = 0; k < 64; ++k) w1c[k] = w1[k * 64 + c];
    float b1c = b1[c];
    __shared__ float s_h[8][64];
    __shared__ float s_t[8][64];
    for (int i = c; i < 512; i += 64)
        s_h[i >> 6][i & 63] = hin[node0 * 64 + i] + gb[i & 63];
    __syncthreads();
    #pragma unroll
    for (int m = 0; m < 8; ++m) {
        float a = b1c;
        #pragma unroll 16
        for (int k = 0; k < 64; ++k) a += s_h[m][k] * w1c[k];
        s_t[m][c] = fmaxf(a, 0.f);
    }
    __syncthreads();
    if (c < 32) {
        int m = c >> 2, j = c & 3;
        float a = b2[j];
        #pragma unroll 16
        for (int k = 0; k < 64; ++k) a += s_t[m][k] * w2[k * 4 + j];
        out[(node0 + m) * 4 + j] = a;
    }
}

extern "C" void kernel_launch(void* const* d_in, const int* in_sizes, int n_in,
                              void* d_out, int out_size, void* d_ws, size_t ws_size,
                              hipStream_t stream) {
    const float* x      = (const float*)d_in[0];
    const int*   ei     = (const int*)d_in[1];
    const float* enc_w1 = (const float*)d_in[2];
    const float* enc_b1 = (const float*)d_in[3];
    const float* enc_w2 = (const float*)d_in[4];
    const float* enc_b2 = (const float*)d_in[5];
    const float* g1_w   = (const float*)d_in[6];
    const float* g1_as  = (const float*)d_in[7];
    const float* g1_ad  = (const float*)d_in[8];
    const float* g1_b   = (const float*)d_in[9];
    const float* g2_w   = (const float*)d_in[10];
    const float* g2_as  = (const float*)d_in[11];
    const float* g2_ad  = (const float*)d_in[12];
    const float* g2_b   = (const float*)d_in[13];
    const float* dec_w1 = (const float*)d_in[14];
    const float* dec_b1 = (const float*)d_in[15];
    const float* dec_w2 = (const float*)d_in[16];
    const float* dec_b2 = (const float*)d_in[17];

    const int N = N_NODES, ET = ET_EDGES;

    // workspace layout (floats)
    float* ws   = (float*)d_ws;
    float* henc = ws;                        //  3,200,000
    float* agg  = ws + 3200000;              // 12,800,000
    float* h2   = ws + 16000000;             //  3,200,000
    float* out2 = ws + 19200000;             //  3,200,000
    float* as1  = ws + 22400000;             //    200,000
    float* ad1  = as1 + 200000;
    float* as2  = ad1 + 200000;
    float* ad2  = as2 + 200000;
    float* wsf  = ad2 + 200000;              // 256
    float* wdf  = wsf + 256;                 // 256
    int*   ib      = (int*)(ws + 23201024);
    int*   deg     = ib;                     // 50,001
    int*   rowp    = ib + 50004;             // 50,001
    int*   cursor  = ib + 100008;            // 50,001
    int*   bsum    = ib + 150012;            // 64
    int*   boff    = ib + 150076;            // 64
    int*   csr_src = ib + 150140;            // 850,000

    // CSR build (multi-block scan)
    hipMemsetAsync(deg, 0, (size_t)N * sizeof(int), stream);
    count_kernel<<<(ET + 255) / 256, 256, 0, stream>>>(ei, deg);
    scanA_kernel<<<NBLK, 1024, 0, stream>>>(deg, rowp, bsum);
    scanB_kernel<<<1, 64, 0, stream>>>(bsum, boff, rowp);
    scanC_kernel<<<(N + 255) / 256, 256, 0, stream>>>(rowp, boff, cursor);
    scatter_kernel<<<(ET + 255) / 256, 256, 0, stream>>>(ei, cursor, csr_src);

    // fold attention vectors, encoder, attention scalars
    fold1_kernel<<<1, 256, 0, stream>>>(g1_w, g1_as, g1_ad, wsf, wdf);
    encoder8_kernel<<<N / 8, 64, 0, stream>>>(x, enc_w1, enc_b1, enc_w2, enc_b2, henc);
    alpha1_kernel<<<N, 256, 0, stream>>>(henc, wsf, wdf, as1, ad1);

    // GAT1: aggregate in henc-domain, then fused GEMM + ELU + GAT2 transform
    aggregate1_kernel<<<(N + 3) / 4, 256, 0, stream>>>(rowp, csr_src, as1, ad1, henc, agg);
    gat1_finish_kernel<<<N / 8, 256, 0, stream>>>(agg, g1_w, g1_b, g2_w, h2);

    // GAT2
    alpha2_kernel<<<N * 4 * 16 / 256, 256, 0, stream>>>(h2, g2_as, g2_ad, as2, ad2);
    aggregate2_kernel<<<(N + 3) / 4, 256, 0, stream>>>(rowp, csr_src, as2, ad2, h2, out2);

    decoder8_kernel<<<N / 8, 64, 0, stream>>>(out2, g2_b, dec_w1, dec_b1, dec_w2, dec_b2, (float*)d_out);
}

// Round 4
// 470.205 us; speedup vs baseline: 9.5352x; 1.3980x over previous
//
#include <hip/hip_runtime.h>
#include <hip/hip_bf16.h>

#define N_NODES 50000
#define N_EDGES 800000
#define ET_EDGES 850000   // + self loops
#define HEADS 4
#define NBLK 49           // ceil(N_NODES/1024)

__device__ __forceinline__ float lrelu(float v) { return v > 0.f ? v : 0.2f * v; }

__device__ __forceinline__ void edge_sd(const int* __restrict__ ei, int e, int& s, int& d) {
    if (e < N_EDGES) { s = ei[e]; d = ei[N_EDGES + e]; }
    else { s = d = e - N_EDGES; }
}

// ---------------- CSR build ----------------
__global__ __launch_bounds__(256) void count_kernel(const int* __restrict__ ei, int* __restrict__ deg) {
    int e = blockIdx.x * 256 + threadIdx.x;
    if (e >= ET_EDGES) return;
    int s, d; edge_sd(ei, e, s, d);
    atomicAdd(deg + d, 1);
}

// phase A: per-1024-block exclusive scan + block sums
__global__ __launch_bounds__(1024) void scanA_kernel(const int* __restrict__ deg,
                                                     int* __restrict__ rowp, int* __restrict__ bsum) {
    __shared__ int s[1024];
    int tid = threadIdx.x;
    int i = blockIdx.x * 1024 + tid;
    int v = (i < N_NODES) ? deg[i] : 0;
    s[tid] = v;
    __syncthreads();
    for (int off = 1; off < 1024; off <<= 1) {
        int t = (tid >= off) ? s[tid - off] : 0;
        __syncthreads();
        s[tid] += t;
        __syncthreads();
    }
    if (i < N_NODES) rowp[i] = s[tid] - v;          // exclusive within block
    if (tid == 1023) bsum[blockIdx.x] = s[1023];    // block total
}

// phase B: scan the 49 block sums (single wave)
__global__ __launch_bounds__(64) void scanB_kernel(const int* __restrict__ bsum,
                                                   int* __restrict__ boff, int* __restrict__ rowp) {
    int lane = threadIdx.x;
    int v = (lane < NBLK) ? bsum[lane] : 0;
    int x = v;
    #pragma unroll
    for (int off = 1; off < 64; off <<= 1) {
        int t = __shfl_up(x, off);
        if (lane >= off) x += t;
    }
    if (lane < NBLK) boff[lane] = x - v;            // exclusive
    if (lane == NBLK - 1) rowp[N_NODES] = x;        // grand total
}

// phase C: add block offsets, fill cursor
__global__ __launch_bounds__(256) void scanC_kernel(int* __restrict__ rowp,
                                                    const int* __restrict__ boff, int* __restrict__ cursor) {
    int i = blockIdx.x * 256 + threadIdx.x;
    if (i >= N_NODES) return;
    int v = rowp[i] + boff[i >> 10];
    rowp[i] = v;
    cursor[i] = v;
}

__global__ __launch_bounds__(256) void scatter_kernel(const int* __restrict__ ei,
                                                      int* __restrict__ cursor, int* __restrict__ csr_src) {
    int e = blockIdx.x * 256 + threadIdx.x;
    if (e >= ET_EDGES) return;
    int s, d; edge_sd(ei, e, s, d);
    int pos = atomicAdd(cursor + d, 1);
    csr_src[pos] = s;
}

// ---------------- fold attention vectors through g1_w: w~[h,k] = sum_c W[k,h*64+c]*a[h,c] ----------------
__global__ __launch_bounds__(256) void fold1_kernel(
    const float* __restrict__ g1w, const float* __restrict__ g1as, const float* __restrict__ g1ad,
    float* __restrict__ wsf, float* __restrict__ wdf) {
    int tid = threadIdx.x;       // tid = h*64+k
    int h = tid >> 6, k = tid & 63;
    float as_acc = 0.f, ad_acc = 0.f;
    #pragma unroll 8
    for (int c = 0; c < 64; ++c) {
        float w = g1w[k * 256 + h * 64 + c];
        as_acc += w * g1as[h * 64 + c];
        ad_acc += w * g1ad[h * 64 + c];
    }
    wsf[tid] = as_acc;
    wdf[tid] = ad_acc;
}

// ---------------- encoder: 32 nodes/block, weights in LDS (no scratch spills!) ----------------
__global__ __launch_bounds__(256) void encoder32_kernel(
    const float* __restrict__ x, const float* __restrict__ w1, const float* __restrict__ b1,
    const float* __restrict__ w2, const float* __restrict__ b2, float* __restrict__ henc) {
    __shared__ float s_w2[4096];     // 16 KB: w2[64][64]
    __shared__ float s_t[32][64];
    __shared__ float s_x[32][8];
    int tid = threadIdx.x;
    int node0 = blockIdx.x * 32;
    for (int i = tid; i < 4096; i += 256) s_w2[i] = w2[i];
    for (int i = tid; i < 224; i += 256) {
        int src = node0 * 7 + i;
        s_x[i / 7][i % 7] = (src < N_NODES * 7) ? x[src] : 0.f;
    }
    int c = tid & 63;
    int mg = tid >> 6;               // node group: nodes mg*8 .. mg*8+7
    float w1c[7];
    #pragma unroll
    for (int k = 0; k < 7; ++k) w1c[k] = w1[k * 64 + c];
    float b1c = b1[c];
    __syncthreads();
    #pragma unroll
    for (int m = 0; m < 8; ++m) {
        int nn = mg * 8 + m;
        float a = b1c;
        #pragma unroll
        for (int k = 0; k < 7; ++k) a += s_x[nn][k] * w1c[k];
        s_t[nn][c] = fmaxf(a, 0.f);
    }
    __syncthreads();
    float acc[8];
    float b2c = b2[c];
    #pragma unroll
    for (int m = 0; m < 8; ++m) acc[m] = b2c;
    #pragma unroll 4
    for (int k = 0; k < 64; ++k) {
        float w = s_w2[k * 64 + c];
        #pragma unroll
        for (int m = 0; m < 8; ++m) acc[m] += s_t[mg * 8 + m][k] * w;
    }
    #pragma unroll
    for (int m = 0; m < 8; ++m) {
        int node = node0 + mg * 8 + m;
        if (node < N_NODES) henc[node * 64 + c] = acc[m];
    }
}

// ---------------- attention scalars from henc: as1[n,h] = henc[n]·wsf[h] ----------------
__global__ __launch_bounds__(256) void alpha1_kernel(
    const float* __restrict__ henc, const float* __restrict__ wsf, const float* __restrict__ wdf,
    float* __restrict__ as_out, float* __restrict__ ad_out) {
    int n = blockIdx.x;                 // one node per block, wave per head
    int r = threadIdx.x;
    int h = r >> 6, k = r & 63;
    float v = henc[n * 64 + k];
    float vs = v * wsf[h * 64 + k];
    float vd = v * wdf[h * 64 + k];
    #pragma unroll
    for (int off = 32; off > 0; off >>= 1) {
        vs += __shfl_xor(vs, off);
        vd += __shfl_xor(vd, off);
    }
    if (k == 0) {
        as_out[n * 4 + h] = vs;
        ad_out[n * 4 + h] = vd;
    }
}

// ---------------- GAT1 aggregation in henc-domain: agg[n][k*4+h] = sum_e alpha[e,h]*henc[src][k] ----------------
__global__ __launch_bounds__(256) void aggregate1_kernel(
    const int* __restrict__ row, const int* __restrict__ csr_src,
    const float* __restrict__ as, const float* __restrict__ ad,
    const float* __restrict__ henc, float* __restrict__ agg) {
    int wslot = threadIdx.x >> 6;
    int lane  = threadIdx.x & 63;
    int n = blockIdx.x * 4 + wslot;
    __shared__ int   ls[4][64];
    __shared__ float lp[4][256];
    if (n >= N_NODES) return;
    int base = row[n];
    int deg  = row[n + 1] - base;
    float4 add = *(const float4*)(ad + n * 4);

    // pass 1: per-head max
    float4 m = make_float4(-1e30f, -1e30f, -1e30f, -1e30f);
    for (int c0 = 0; c0 < deg; c0 += 64) {
        int j = c0 + lane;
        float4 e = make_float4(-1e30f, -1e30f, -1e30f, -1e30f);
        if (j < deg) {
            int s = csr_src[base + j];
            float4 a = *(const float4*)(as + s * 4);
            e.x = lrelu(a.x + add.x); e.y = lrelu(a.y + add.y);
            e.z = lrelu(a.z + add.z); e.w = lrelu(a.w + add.w);
        }
        #pragma unroll
        for (int off = 32; off > 0; off >>= 1) {
            e.x = fmaxf(e.x, __shfl_xor(e.x, off));
            e.y = fmaxf(e.y, __shfl_xor(e.y, off));
            e.z = fmaxf(e.z, __shfl_xor(e.z, off));
            e.w = fmaxf(e.w, __shfl_xor(e.w, off));
        }
        m.x = fmaxf(m.x, e.x); m.y = fmaxf(m.y, e.y);
        m.z = fmaxf(m.z, e.z); m.w = fmaxf(m.w, e.w);
    }

    // pass 2: exp + denom + accumulate henc (lane = channel k)
    float4 l = make_float4(0.f, 0.f, 0.f, 0.f);
    float4 acc = make_float4(0.f, 0.f, 0.f, 0.f);   // per-head accumulators
    for (int c0 = 0; c0 < deg; c0 += 64) {
        int j = c0 + lane;
        int s = 0;
        float4 p = make_float4(0.f, 0.f, 0.f, 0.f);
        if (j < deg) {
            s = csr_src[base + j];
            float4 a = *(const float4*)(as + s * 4);
            p.x = __expf(lrelu(a.x + add.x) - m.x);
            p.y = __expf(lrelu(a.y + add.y) - m.y);
            p.z = __expf(lrelu(a.z + add.z) - m.z);
            p.w = __expf(lrelu(a.w + add.w) - m.w);
        }
        ls[wslot][lane] = s;
        *(float4*)(&lp[wslot][lane * 4]) = p;
        float4 t = p;
        #pragma unroll
        for (int off = 32; off > 0; off >>= 1) {
            t.x += __shfl_xor(t.x, off);
            t.y += __shfl_xor(t.y, off);
            t.z += __shfl_xor(t.z, off);
            t.w += __shfl_xor(t.w, off);
        }
        l.x += t.x; l.y += t.y; l.z += t.z; l.w += t.w;
        int cnt = min(64, deg - c0);
        for (int j2 = 0; j2 < cnt; ++j2) {
            int sj = ls[wslot][j2];
            float4 pj = *(const float4*)(&lp[wslot][j2 * 4]);
            float v = henc[sj * 64 + lane];
            acc.x += pj.x * v; acc.y += pj.y * v;
            acc.z += pj.z * v; acc.w += pj.w * v;
        }
    }
    float4 r;
    r.x = acc.x / (l.x + 1e-16f);
    r.y = acc.y / (l.y + 1e-16f);
    r.z = acc.z / (l.z + 1e-16f);
    r.w = acc.w / (l.w + 1e-16f);
    *(float4*)(agg + (size_t)n * 256 + lane * 4) = r;
}

// ---------------- fused: out1 = agg @ W_h (+b1, ELU) ; h2 = elu(out1) @ g2_w. 8 nodes/block ----------------
__global__ __launch_bounds__(256) void gat1_finish_kernel(
    const float* __restrict__ agg, const float* __restrict__ g1w, const float* __restrict__ g1b,
    const float* __restrict__ g2w, float* __restrict__ h2) {
    int tid = threadIdx.x;
    int node0 = blockIdx.x * 8;
    __shared__ float s_agg[8][256];
    __shared__ float s_v[8][256];
    for (int i = tid; i < 8 * 256; i += 256)
        s_agg[i >> 8][i & 255] = agg[(size_t)node0 * 256 + i];
    __syncthreads();
    int h = tid >> 6;
    float accv[8] = {0.f, 0.f, 0.f, 0.f, 0.f, 0.f, 0.f, 0.f};
    for (int k = 0; k < 64; ++k) {
        float w = g1w[k * 256 + tid];
        #pragma unroll
        for (int m = 0; m < 8; ++m) accv[m] += s_agg[m][k * 4 + h] * w;
    }
    float bias = g1b[tid];
    #pragma unroll
    for (int m = 0; m < 8; ++m) {
        float v = accv[m] + bias;
        s_v[m][tid] = v > 0.f ? v : expm1f(v);   // ELU
    }
    __syncthreads();
    int m1 = tid >> 6;           // nodes m1 and m1+4
    int c2 = tid & 63;
    float a0 = 0.f, a1 = 0.f;
    for (int k = 0; k < 256; ++k) {
        float w = g2w[k * 64 + c2];
        a0 += s_v[m1][k] * w;
        a1 += s_v[m1 + 4][k] * w;
    }
    h2[(node0 + m1) * 64 + c2] = a0;
    h2[(node0 + m1 + 4) * 64 + c2] = a1;
}

// ---------------- per-(node,head) attention scalars for layer 2 ----------------
__global__ __launch_bounds__(256) void alpha2_kernel(
    const float* __restrict__ h, const float* __restrict__ a_src, const float* __restrict__ a_dst,
    float* __restrict__ as_out, float* __restrict__ ad_out) {
    int idx = blockIdx.x * 256 + threadIdx.x;   // over N*4*16 exactly
    int k = idx & 15;
    int g = idx >> 4;
    int hd = g & 3;
    int n = g >> 2;
    if (n >= N_NODES) return;
    float v = h[n * 64 + hd * 16 + k];
    float vs = v * a_src[hd * 16 + k];
    float vd = v * a_dst[hd * 16 + k];
    #pragma unroll
    for (int off = 8; off > 0; off >>= 1) {
        vs += __shfl_xor(vs, off);
        vd += __shfl_xor(vd, off);
    }
    if (k == 0) {
        as_out[n * 4 + hd] = vs;
        ad_out[n * 4 + hd] = vd;
    }
}

// ---------------- GAT2 dst-centric aggregate (post-transform, 64-float rows) ----------------
__global__ __launch_bounds__(256) void aggregate2_kernel(
    const int* __restrict__ row, const int* __restrict__ csr_src,
    const float* __restrict__ as, const float* __restrict__ ad,
    const float* __restrict__ h, float* __restrict__ out) {
    int wslot = threadIdx.x >> 6;
    int lane  = threadIdx.x & 63;
    int n = blockIdx.x * 4 + wslot;
    __shared__ int   ls[4][64];
    __shared__ float lp[4][256];
    if (n >= N_NODES) return;
    int base = row[n];
    int deg  = row[n + 1] - base;
    int head = lane >> 4;
    float4 add = *(const float4*)(ad + n * 4);

    float4 m = make_float4(-1e30f, -1e30f, -1e30f, -1e30f);
    for (int c0 = 0; c0 < deg; c0 += 64) {
        int j = c0 + lane;
        float4 e = make_float4(-1e30f, -1e30f, -1e30f, -1e30f);
        if (j < deg) {
            int s = csr_src[base + j];
            float4 a = *(const float4*)(as + s * 4);
            e.x = lrelu(a.x + add.x); e.y = lrelu(a.y + add.y);
            e.z = lrelu(a.z + add.z); e.w = lrelu(a.w + add.w);
        }
        #pragma unroll
        for (int off = 32; off > 0; off >>= 1) {
            e.x = fmaxf(e.x, __shfl_xor(e.x, off));
            e.y = fmaxf(e.y, __shfl_xor(e.y, off));
            e.z = fmaxf(e.z, __shfl_xor(e.z, off));
            e.w = fmaxf(e.w, __shfl_xor(e.w, off));
        }
        m.x = fmaxf(m.x, e.x); m.y = fmaxf(m.y, e.y);
        m.z = fmaxf(m.z, e.z); m.w = fmaxf(m.w, e.w);
    }

    float4 l = make_float4(0.f, 0.f, 0.f, 0.f);
    float acc = 0.f;
    for (int c0 = 0; c0 < deg; c0 += 64) {
        int j = c0 + lane;
        int s = 0;
        float4 p = make_float4(0.f, 0.f, 0.f, 0.f);
        if (j < deg) {
            s = csr_src[base + j];
            float4 a = *(const float4*)(as + s * 4);
            p.x = __expf(lrelu(a.x + add.x) - m.x);
            p.y = __expf(lrelu(a.y + add.y) - m.y);
            p.z = __expf(lrelu(a.z + add.z) - m.z);
            p.w = __expf(lrelu(a.w + add.w) - m.w);
        }
        ls[wslot][lane] = s;
        *(float4*)(&lp[wslot][lane * 4]) = p;
        float4 t = p;
        #pragma unroll
        for (int off = 32; off > 0; off >>= 1) {
            t.x += __shfl_xor(t.x, off);
            t.y += __shfl_xor(t.y, off);
            t.z += __shfl_xor(t.z, off);
            t.w += __shfl_xor(t.w, off);
        }
        l.x += t.x; l.y += t.y; l.z += t.z; l.w += t.w;
        int cnt = min(64, deg - c0);
        for (int j2 = 0; j2 < cnt; ++j2) {
            int sj = ls[wslot][j2];
            float pj = lp[wslot][j2 * 4 + head];
            acc += pj * h[sj * 64 + lane];
        }
    }
    float lh = (head == 0) ? l.x : (head == 1) ? l.y : (head == 2) ? l.z : l.w;
    out[(size_t)n * 64 + lane] = acc / (lh + 1e-16f);
}

// ---------------- decoder: 32 nodes/block, dec_w1 in LDS (no scratch spills!) ----------------
__global__ __launch_bounds__(256) void decoder32_kernel(
    const float* __restrict__ hin, const float* __restrict__ gb,
    const float* __restrict__ w1, const float* __restrict__ b1,
    const float* __restrict__ w2, const float* __restrict__ b2, float* __restrict__ out) {
    __shared__ float s_w1[4096];     // 16 KB
    __shared__ float s_w2[256];
    __shared__ float s_h[32][64];
    __shared__ float s_t[32][64];
    int tid = threadIdx.x;
    int node0 = blockIdx.x * 32;
    for (int i = tid; i < 4096; i += 256) s_w1[i] = w1[i];
    if (tid < 256) s_w2[tid] = w2[tid];
    for (int i = tid; i < 2048; i += 256) {
        int nn = i >> 6, k = i & 63;
        int node = node0 + nn;
        s_h[nn][k] = (node < N_NODES ? hin[(size_t)node * 64 + k] : 0.f) + gb[k];
    }
    __syncthreads();
    int c = tid & 63;
    int mg = tid >> 6;
    float b1c = b1[c];
    float acc[8];
    #pragma unroll
    for (int m = 0; m < 8; ++m) acc[m] = b1c;
    #pragma unroll 4
    for (int k = 0; k < 64; ++k) {
        float w = s_w1[k * 64 + c];
        #pragma unroll
        for (int m = 0; m < 8; ++m) acc[m] += s_h[mg * 8 + m][k] * w;
    }
    #pragma unroll
    for (int m = 0; m < 8; ++m) s_t[mg * 8 + m][c] = fmaxf(acc[m], 0.f);
    __syncthreads();
    if (tid < 128) {
        int m = tid >> 2, j = tid & 3;
        int node = node0 + m;
        if (node < N_NODES) {
            float a = b2[j];
            #pragma unroll 16
            for (int k = 0; k < 64; ++k) a += s_t[m][k] * s_w2[k * 4 + j];
            out[node * 4 + j] = a;
        }
    }
}

extern "C" void kernel_launch(void* const* d_in, const int* in_sizes, int n_in,
                              void* d_out, int out_size, void* d_ws, size_t ws_size,
                              hipStream_t stream) {
    const float* x      = (const float*)d_in[0];
    const int*   ei     = (const int*)d_in[1];
    const float* enc_w1 = (const float*)d_in[2];
    const float* enc_b1 = (const float*)d_in[3];
    const float* enc_w2 = (const float*)d_in[4];
    const float* enc_b2 = (const float*)d_in[5];
    const float* g1_w   = (const float*)d_in[6];
    const float* g1_as  = (const float*)d_in[7];
    const float* g1_ad  = (const float*)d_in[8];
    const float* g1_b   = (const float*)d_in[9];
    const float* g2_w   = (const float*)d_in[10];
    const float* g2_as  = (const float*)d_in[11];
    const float* g2_ad  = (const float*)d_in[12];
    const float* g2_b   = (const float*)d_in[13];
    const float* dec_w1 = (const float*)d_in[14];
    const float* dec_b1 = (const float*)d_in[15];
    const float* dec_w2 = (const float*)d_in[16];
    const float* dec_b2 = (const float*)d_in[17];

    const int N = N_NODES, ET = ET_EDGES;

    // workspace layout (floats)
    float* ws   = (float*)d_ws;
    float* henc = ws;                        //  3,200,000
    float* agg  = ws + 3200000;              // 12,800,000
    float* h2   = ws + 16000000;             //  3,200,000
    float* out2 = ws + 19200000;             //  3,200,000
    float* as1  = ws + 22400000;             //    200,000
    float* ad1  = as1 + 200000;
    float* as2  = ad1 + 200000;
    float* ad2  = as2 + 200000;
    float* wsf  = ad2 + 200000;              // 256
    float* wdf  = wsf + 256;                 // 256
    int*   ib      = (int*)(ws + 23201024);
    int*   deg     = ib;                     // 50,001
    int*   rowp    = ib + 50004;             // 50,001
    int*   cursor  = ib + 100008;            // 50,001
    int*   bsum    = ib + 150012;            // 64
    int*   boff    = ib + 150076;            // 64
    int*   csr_src = ib + 150140;            // 850,000

    // CSR build (multi-block scan)
    hipMemsetAsync(deg, 0, (size_t)N * sizeof(int), stream);
    count_kernel<<<(ET + 255) / 256, 256, 0, stream>>>(ei, deg);
    scanA_kernel<<<NBLK, 1024, 0, stream>>>(deg, rowp, bsum);
    scanB_kernel<<<1, 64, 0, stream>>>(bsum, boff, rowp);
    scanC_kernel<<<(N + 255) / 256, 256, 0, stream>>>(rowp, boff, cursor);
    scatter_kernel<<<(ET + 255) / 256, 256, 0, stream>>>(ei, cursor, csr_src);

    // fold attention vectors, encoder, attention scalars
    fold1_kernel<<<1, 256, 0, stream>>>(g1_w, g1_as, g1_ad, wsf, wdf);
    encoder32_kernel<<<(N + 31) / 32, 256, 0, stream>>>(x, enc_w1, enc_b1, enc_w2, enc_b2, henc);
    alpha1_kernel<<<N, 256, 0, stream>>>(henc, wsf, wdf, as1, ad1);

    // GAT1: aggregate in henc-domain, then fused GEMM + ELU + GAT2 transform
    aggregate1_kernel<<<(N + 3) / 4, 256, 0, stream>>>(rowp, csr_src, as1, ad1, henc, agg);
    gat1_finish_kernel<<<N / 8, 256, 0, stream>>>(agg, g1_w, g1_b, g2_w, h2);

    // GAT2
    alpha2_kernel<<<N * 4 * 16 / 256, 256, 0, stream>>>(h2, g2_as, g2_ad, as2, ad2);
    aggregate2_kernel<<<(N + 3) / 4, 256, 0, stream>>>(rowp, csr_src, as2, ad2, h2, out2);

    decoder32_kernel<<<(N + 31) / 32, 256, 0, stream>>>(out2, g2_b, dec_w1, dec_b1, dec_w2, dec_b2, (float*)d_out);
}

// Round 5
// 416.952 us; speedup vs baseline: 10.7530x; 1.1277x over previous
//
#include <hip/hip_runtime.h>
#include <hip/hip_bf16.h>

#define N_NODES 50000
#define N_EDGES 800000
#define ET_EDGES 850000   // + self loops
#define HEADS 4
#define NBLK 49           // ceil(N_NODES/1024)

__device__ __forceinline__ float lrelu(float v) { return v > 0.f ? v : 0.2f * v; }

__device__ __forceinline__ void edge_sd(const int* __restrict__ ei, int e, int& s, int& d) {
    if (e < N_EDGES) { s = ei[e]; d = ei[N_EDGES + e]; }
    else { s = d = e - N_EDGES; }
}

// ---------------- CSR build ----------------
__global__ __launch_bounds__(256) void count_kernel(const int* __restrict__ ei, int* __restrict__ deg) {
    int e = blockIdx.x * 256 + threadIdx.x;
    if (e >= ET_EDGES) return;
    int s, d; edge_sd(ei, e, s, d);
    atomicAdd(deg + d, 1);
}

__global__ __launch_bounds__(1024) void scanA_kernel(const int* __restrict__ deg,
                                                     int* __restrict__ rowp, int* __restrict__ bsum) {
    __shared__ int s[1024];
    int tid = threadIdx.x;
    int i = blockIdx.x * 1024 + tid;
    int v = (i < N_NODES) ? deg[i] : 0;
    s[tid] = v;
    __syncthreads();
    for (int off = 1; off < 1024; off <<= 1) {
        int t = (tid >= off) ? s[tid - off] : 0;
        __syncthreads();
        s[tid] += t;
        __syncthreads();
    }
    if (i < N_NODES) rowp[i] = s[tid] - v;
    if (tid == 1023) bsum[blockIdx.x] = s[1023];
}

__global__ __launch_bounds__(64) void scanB_kernel(const int* __restrict__ bsum,
                                                   int* __restrict__ boff, int* __restrict__ rowp) {
    int lane = threadIdx.x;
    int v = (lane < NBLK) ? bsum[lane] : 0;
    int x = v;
    #pragma unroll
    for (int off = 1; off < 64; off <<= 1) {
        int t = __shfl_up(x, off);
        if (lane >= off) x += t;
    }
    if (lane < NBLK) boff[lane] = x - v;
    if (lane == NBLK - 1) rowp[N_NODES] = x;
}

__global__ __launch_bounds__(256) void scanC_kernel(int* __restrict__ rowp,
                                                    const int* __restrict__ boff, int* __restrict__ cursor) {
    int i = blockIdx.x * 256 + threadIdx.x;
    if (i >= N_NODES) return;
    int v = rowp[i] + boff[i >> 10];
    rowp[i] = v;
    cursor[i] = v;
}

__global__ __launch_bounds__(256) void scatter_kernel(const int* __restrict__ ei,
                                                      int* __restrict__ cursor, int* __restrict__ csr_src) {
    int e = blockIdx.x * 256 + threadIdx.x;
    if (e >= ET_EDGES) return;
    int s, d; edge_sd(ei, e, s, d);
    int pos = atomicAdd(cursor + d, 1);
    csr_src[pos] = s;
}

// ---------------- fold attention vectors through g1_w ----------------
__global__ __launch_bounds__(256) void fold1_kernel(
    const float* __restrict__ g1w, const float* __restrict__ g1as, const float* __restrict__ g1ad,
    float* __restrict__ wsf, float* __restrict__ wdf) {
    int tid = threadIdx.x;       // tid = h*64+k
    int h = tid >> 6, k = tid & 63;
    float as_acc = 0.f, ad_acc = 0.f;
    #pragma unroll 8
    for (int c = 0; c < 64; ++c) {
        float w = g1w[k * 256 + h * 64 + c];
        as_acc += w * g1as[h * 64 + c];
        ad_acc += w * g1ad[h * 64 + c];
    }
    wsf[tid] = as_acc;
    wdf[tid] = ad_acc;
}

// ---------------- encoder (32 nodes/block) + fused alpha1 ----------------
__global__ __launch_bounds__(256) void encoder32_kernel(
    const float* __restrict__ x, const float* __restrict__ w1, const float* __restrict__ b1,
    const float* __restrict__ w2, const float* __restrict__ b2,
    const float* __restrict__ wsf, const float* __restrict__ wdf,
    float* __restrict__ henc, float* __restrict__ as1, float* __restrict__ ad1) {
    __shared__ float s_w2[4096];     // w2[64][64]
    __shared__ float s_t[32][64];
    __shared__ float s_x[32][8];
    __shared__ float s_he[32][65];   // +1 pad: conflict-free alpha reads
    __shared__ float s_wf[8 * 65];   // [comp*4+h][k] pad 65
    int tid = threadIdx.x;
    int node0 = blockIdx.x * 32;
    for (int i = tid; i < 4096; i += 256) s_w2[i] = w2[i];
    for (int i = tid; i < 224; i += 256) {
        int src = node0 * 7 + i;
        s_x[i / 7][i % 7] = (src < N_NODES * 7) ? x[src] : 0.f;
    }
    for (int i = tid; i < 512; i += 256) {
        int g = i >> 6, k = i & 63;
        int h = g & 3;
        s_wf[g * 65 + k] = (g < 4) ? wsf[h * 64 + k] : wdf[h * 64 + k];
    }
    int c = tid & 63;
    int mg = tid >> 6;               // node group: nodes mg*8 .. mg*8+7
    float w1c[7];
    #pragma unroll
    for (int k = 0; k < 7; ++k) w1c[k] = w1[k * 64 + c];
    float b1c = b1[c];
    __syncthreads();
    #pragma unroll
    for (int m = 0; m < 8; ++m) {
        int nn = mg * 8 + m;
        float a = b1c;
        #pragma unroll
        for (int k = 0; k < 7; ++k) a += s_x[nn][k] * w1c[k];
        s_t[nn][c] = fmaxf(a, 0.f);
    }
    __syncthreads();
    float acc[8];
    float b2c = b2[c];
    #pragma unroll
    for (int m = 0; m < 8; ++m) acc[m] = b2c;
    #pragma unroll 4
    for (int k = 0; k < 64; ++k) {
        float w = s_w2[k * 64 + c];
        #pragma unroll
        for (int m = 0; m < 8; ++m) acc[m] += s_t[mg * 8 + m][k] * w;
    }
    #pragma unroll
    for (int m = 0; m < 8; ++m) {
        int nn = mg * 8 + m;
        int node = node0 + nn;
        s_he[nn][c] = acc[m];
        if (node < N_NODES) henc[node * 64 + c] = acc[m];
    }
    __syncthreads();
    // fused alpha1: thread = (node nn, r): r = comp*4 + h
    {
        int nn = tid >> 3, r = tid & 7;
        int node = node0 + nn;
        const float* wf = s_wf + r * 65;
        float sum = 0.f;
        #pragma unroll 8
        for (int k = 0; k < 64; ++k) sum += s_he[nn][k] * wf[k];
        if (node < N_NODES) {
            int hh = r & 3;
            if (r < 4) as1[node * 4 + hh] = sum;
            else       ad1[node * 4 + hh] = sum;
        }
    }
}

// ---------------- GAT1 aggregation in henc-domain (unroll-4 gather) ----------------
__global__ __launch_bounds__(256) void aggregate1_kernel(
    const int* __restrict__ row, const int* __restrict__ csr_src,
    const float* __restrict__ as, const float* __restrict__ ad,
    const float* __restrict__ henc, float* __restrict__ agg) {
    int wslot = threadIdx.x >> 6;
    int lane  = threadIdx.x & 63;
    int n = blockIdx.x * 4 + wslot;
    __shared__ int    ls[4][64];
    __shared__ float4 lp4[4][64];
    if (n >= N_NODES) return;
    int base = row[n];
    int deg  = row[n + 1] - base;
    float4 add = *(const float4*)(ad + n * 4);

    // pass 1: per-head max
    float4 m = make_float4(-1e30f, -1e30f, -1e30f, -1e30f);
    for (int c0 = 0; c0 < deg; c0 += 64) {
        int j = c0 + lane;
        float4 e = make_float4(-1e30f, -1e30f, -1e30f, -1e30f);
        if (j < deg) {
            int s = csr_src[base + j];
            float4 a = *(const float4*)(as + s * 4);
            e.x = lrelu(a.x + add.x); e.y = lrelu(a.y + add.y);
            e.z = lrelu(a.z + add.z); e.w = lrelu(a.w + add.w);
        }
        #pragma unroll
        for (int off = 32; off > 0; off >>= 1) {
            e.x = fmaxf(e.x, __shfl_xor(e.x, off));
            e.y = fmaxf(e.y, __shfl_xor(e.y, off));
            e.z = fmaxf(e.z, __shfl_xor(e.z, off));
            e.w = fmaxf(e.w, __shfl_xor(e.w, off));
        }
        m.x = fmaxf(m.x, e.x); m.y = fmaxf(m.y, e.y);
        m.z = fmaxf(m.z, e.z); m.w = fmaxf(m.w, e.w);
    }

    // pass 2: exp + denom + accumulate henc (lane = channel k)
    float4 l = make_float4(0.f, 0.f, 0.f, 0.f);
    float4 acc = make_float4(0.f, 0.f, 0.f, 0.f);
    for (int c0 = 0; c0 < deg; c0 += 64) {
        int j = c0 + lane;
        int s = 0;
        float4 p = make_float4(0.f, 0.f, 0.f, 0.f);
        if (j < deg) {
            s = csr_src[base + j];
            float4 a = *(const float4*)(as + s * 4);
            p.x = __expf(lrelu(a.x + add.x) - m.x);
            p.y = __expf(lrelu(a.y + add.y) - m.y);
            p.z = __expf(lrelu(a.z + add.z) - m.z);
            p.w = __expf(lrelu(a.w + add.w) - m.w);
        }
        ls[wslot][lane] = s;
        lp4[wslot][lane] = p;
        float4 t = p;
        #pragma unroll
        for (int off = 32; off > 0; off >>= 1) {
            t.x += __shfl_xor(t.x, off);
            t.y += __shfl_xor(t.y, off);
            t.z += __shfl_xor(t.z, off);
            t.w += __shfl_xor(t.w, off);
        }
        l.x += t.x; l.y += t.y; l.z += t.z; l.w += t.w;
        int cnt = min(64, deg - c0);
        const int*    lsw = ls[wslot];
        const float4* lpw = lp4[wslot];
        int j2 = 0;
        for (; j2 + 4 <= cnt; j2 += 4) {
            int a0 = lsw[j2+0] * 64 + lane;
            int a1 = lsw[j2+1] * 64 + lane;
            int a2 = lsw[j2+2] * 64 + lane;
            int a3 = lsw[j2+3] * 64 + lane;
            float v0 = henc[a0], v1 = henc[a1], v2 = henc[a2], v3 = henc[a3];
            float4 p0 = lpw[j2+0], p1 = lpw[j2+1], p2 = lpw[j2+2], p3 = lpw[j2+3];
            acc.x += p0.x*v0 + p1.x*v1 + p2.x*v2 + p3.x*v3;
            acc.y += p0.y*v0 + p1.y*v1 + p2.y*v2 + p3.y*v3;
            acc.z += p0.z*v0 + p1.z*v1 + p2.z*v2 + p3.z*v3;
            acc.w += p0.w*v0 + p1.w*v1 + p2.w*v2 + p3.w*v3;
        }
        for (; j2 < cnt; ++j2) {
            float v = henc[lsw[j2] * 64 + lane];
            float4 pj = lpw[j2];
            acc.x += pj.x * v; acc.y += pj.y * v;
            acc.z += pj.z * v; acc.w += pj.w * v;
        }
    }
    float4 r;
    r.x = acc.x / (l.x + 1e-16f);
    r.y = acc.y / (l.y + 1e-16f);
    r.z = acc.z / (l.z + 1e-16f);
    r.w = acc.w / (l.w + 1e-16f);
    *(float4*)(agg + (size_t)n * 256 + lane * 4) = r;   // agg[n][k*4+h]
}

// ---------------- fused GEMM1+ELU+GEMM2 + alpha2: 16 nodes/block ----------------
__global__ __launch_bounds__(256) void gat1_finish_kernel(
    const float* __restrict__ agg, const float* __restrict__ g1w, const float* __restrict__ g1b,
    const float* __restrict__ g2w, const float* __restrict__ g2as, const float* __restrict__ g2ad,
    float* __restrict__ h2, float* __restrict__ as2, float* __restrict__ ad2) {
    __shared__ float s_a1[256 * 20];   // [idx=k*4+h][m], stride 20 (pad)
    __shared__ float s_vT[256 * 20];   // [k][m], stride 20 (pad)
    int tid = threadIdx.x;
    int node0 = blockIdx.x * 16;
    for (int i = tid; i < 4096; i += 256) {
        int m = i >> 8, idx = i & 255;
        s_a1[idx * 20 + m] = agg[(size_t)node0 * 256 + i];
    }
    __syncthreads();
    // GEMM1: out1[m][q] = sum_k a1[(k*4+h)][m] * g1w[k*256+q],  h = q>>6
    int q = tid;
    int h = q >> 6;
    float acc1[16];
    #pragma unroll
    for (int m = 0; m < 16; ++m) acc1[m] = 0.f;
    const float* wp = g1w + q;
    const float* ap = s_a1 + h * 20;   // (k*4+h)*20 = k*80 + h*20
    #pragma unroll 4
    for (int k = 0; k < 64; ++k) {
        float w = wp[k * 256];
        const float* a = ap + k * 80;
        #pragma unroll
        for (int g = 0; g < 4; ++g) {
            float4 av = *(const float4*)(a + g * 4);
            acc1[g * 4 + 0] += av.x * w;
            acc1[g * 4 + 1] += av.y * w;
            acc1[g * 4 + 2] += av.z * w;
            acc1[g * 4 + 3] += av.w * w;
        }
    }
    float bias = g1b[q];
    #pragma unroll
    for (int m = 0; m < 16; ++m) {
        float v = acc1[m] + bias;
        s_vT[q * 20 + m] = v > 0.f ? v : expm1f(v);   // ELU
    }
    __syncthreads();
    // GEMM2: h2[m][c] = sum_k vT[k][m] * g2w[k*64+c]; wave wv owns m = wv*4..+3
    int c = tid & 63;
    int wv = tid >> 6;
    float acc2[4] = {0.f, 0.f, 0.f, 0.f};
    const float* w2p = g2w + c;
    const float* vp = s_vT + wv * 4;
    #pragma unroll 4
    for (int k = 0; k < 256; ++k) {
        float w = w2p[k * 64];
        float4 vv = *(const float4*)(vp + k * 20);
        acc2[0] += vv.x * w;
        acc2[1] += vv.y * w;
        acc2[2] += vv.z * w;
        acc2[3] += vv.w * w;
    }
    // write h2 + fused alpha2 (16-lane shuffle reduce; g2as/ad are [h][kk] = [c])
    float ga = g2as[c], gd = g2ad[c];
    int kk = c & 15;
    #pragma unroll
    for (int mm = 0; mm < 4; ++mm) {
        int n = node0 + wv * 4 + mm;
        h2[(size_t)n * 64 + c] = acc2[mm];
        float vs = acc2[mm] * ga;
        float vd = acc2[mm] * gd;
        #pragma unroll
        for (int off = 8; off > 0; off >>= 1) {
            vs += __shfl_xor(vs, off);
            vd += __shfl_xor(vd, off);
        }
        if (kk == 0) {
            as2[n * 4 + (c >> 4)] = vs;
            ad2[n * 4 + (c >> 4)] = vd;
        }
    }
}

// ---------------- GAT2 dst-centric aggregate (unroll-4 gather) ----------------
__global__ __launch_bounds__(256) void aggregate2_kernel(
    const int* __restrict__ row, const int* __restrict__ csr_src,
    const float* __restrict__ as, const float* __restrict__ ad,
    const float* __restrict__ h, float* __restrict__ out) {
    int wslot = threadIdx.x >> 6;
    int lane  = threadIdx.x & 63;
    int n = blockIdx.x * 4 + wslot;
    __shared__ int    ls[4][64];
    __shared__ float4 lp4[4][64];
    if (n >= N_NODES) return;
    int base = row[n];
    int deg  = row[n + 1] - base;
    int head = lane >> 4;
    float4 add = *(const float4*)(ad + n * 4);

    float4 m = make_float4(-1e30f, -1e30f, -1e30f, -1e30f);
    for (int c0 = 0; c0 < deg; c0 += 64) {
        int j = c0 + lane;
        float4 e = make_float4(-1e30f, -1e30f, -1e30f, -1e30f);
        if (j < deg) {
            int s = csr_src[base + j];
            float4 a = *(const float4*)(as + s * 4);
            e.x = lrelu(a.x + add.x); e.y = lrelu(a.y + add.y);
            e.z = lrelu(a.z + add.z); e.w = lrelu(a.w + add.w);
        }
        #pragma unroll
        for (int off = 32; off > 0; off >>= 1) {
            e.x = fmaxf(e.x, __shfl_xor(e.x, off));
            e.y = fmaxf(e.y, __shfl_xor(e.y, off));
            e.z = fmaxf(e.z, __shfl_xor(e.z, off));
            e.w = fmaxf(e.w, __shfl_xor(e.w, off));
        }
        m.x = fmaxf(m.x, e.x); m.y = fmaxf(m.y, e.y);
        m.z = fmaxf(m.z, e.z); m.w = fmaxf(m.w, e.w);
    }

    float4 l = make_float4(0.f, 0.f, 0.f, 0.f);
    float acc = 0.f;
    for (int c0 = 0; c0 < deg; c0 += 64) {
        int j = c0 + lane;
        int s = 0;
        float4 p = make_float4(0.f, 0.f, 0.f, 0.f);
        if (j < deg) {
            s = csr_src[base + j];
            float4 a = *(const float4*)(as + s * 4);
            p.x = __expf(lrelu(a.x + add.x) - m.x);
            p.y = __expf(lrelu(a.y + add.y) - m.y);
            p.z = __expf(lrelu(a.z + add.z) - m.z);
            p.w = __expf(lrelu(a.w + add.w) - m.w);
        }
        ls[wslot][lane] = s;
        lp4[wslot][lane] = p;
        float4 t = p;
        #pragma unroll
        for (int off = 32; off > 0; off >>= 1) {
            t.x += __shfl_xor(t.x, off);
            t.y += __shfl_xor(t.y, off);
            t.z += __shfl_xor(t.z, off);
            t.w += __shfl_xor(t.w, off);
        }
        l.x += t.x; l.y += t.y; l.z += t.z; l.w += t.w;
        int cnt = min(64, deg - c0);
        const int*   lsw = ls[wslot];
        const float* lpf = (const float*)lp4[wslot];
        int j2 = 0;
        for (; j2 + 4 <= cnt; j2 += 4) {
            int a0 = lsw[j2+0] * 64 + lane;
            int a1 = lsw[j2+1] * 64 + lane;
            int a2 = lsw[j2+2] * 64 + lane;
            int a3 = lsw[j2+3] * 64 + lane;
            float v0 = h[a0], v1 = h[a1], v2 = h[a2], v3 = h[a3];
            float p0 = lpf[(j2+0) * 4 + head];
            float p1 = lpf[(j2+1) * 4 + head];
            float p2 = lpf[(j2+2) * 4 + head];
            float p3 = lpf[(j2+3) * 4 + head];
            acc += p0*v0 + p1*v1 + p2*v2 + p3*v3;
        }
        for (; j2 < cnt; ++j2) {
            acc += lpf[j2 * 4 + head] * h[lsw[j2] * 64 + lane];
        }
    }
    float lh = (head == 0) ? l.x : (head == 1) ? l.y : (head == 2) ? l.z : l.w;
    out[(size_t)n * 64 + lane] = acc / (lh + 1e-16f);
}

// ---------------- decoder: 32 nodes/block, w1 in LDS ----------------
__global__ __launch_bounds__(256) void decoder32_kernel(
    const float* __restrict__ hin, const float* __restrict__ gb,
    const float* __restrict__ w1, const float* __restrict__ b1,
    const float* __restrict__ w2, const float* __restrict__ b2, float* __restrict__ out) {
    __shared__ float s_w1[4096];
    __shared__ float s_w2[256];
    __shared__ float s_h[32][64];
    __shared__ float s_t[32][64];
    int tid = threadIdx.x;
    int node0 = blockIdx.x * 32;
    for (int i = tid; i < 4096; i += 256) s_w1[i] = w1[i];
    if (tid < 256) s_w2[tid] = w2[tid];
    for (int i = tid; i < 2048; i += 256) {
        int nn = i >> 6, k = i & 63;
        int node = node0 + nn;
        s_h[nn][k] = (node < N_NODES ? hin[(size_t)node * 64 + k] : 0.f) + gb[k];
    }
    __syncthreads();
    int c = tid & 63;
    int mg = tid >> 6;
    float b1c = b1[c];
    float acc[8];
    #pragma unroll
    for (int m = 0; m < 8; ++m) acc[m] = b1c;
    #pragma unroll 4
    for (int k = 0; k < 64; ++k) {
        float w = s_w1[k * 64 + c];
        #pragma unroll
        for (int m = 0; m < 8; ++m) acc[m] += s_h[mg * 8 + m][k] * w;
    }
    #pragma unroll
    for (int m = 0; m < 8; ++m) s_t[mg * 8 + m][c] = fmaxf(acc[m], 0.f);
    __syncthreads();
    if (tid < 128) {
        int m = tid >> 2, j = tid & 3;
        int node = node0 + m;
        if (node < N_NODES) {
            float a = b2[j];
            #pragma unroll 16
            for (int k = 0; k < 64; ++k) a += s_t[m][k] * s_w2[k * 4 + j];
            out[node * 4 + j] = a;
        }
    }
}

extern "C" void kernel_launch(void* const* d_in, const int* in_sizes, int n_in,
                              void* d_out, int out_size, void* d_ws, size_t ws_size,
                              hipStream_t stream) {
    const float* x      = (const float*)d_in[0];
    const int*   ei     = (const int*)d_in[1];
    const float* enc_w1 = (const float*)d_in[2];
    const float* enc_b1 = (const float*)d_in[3];
    const float* enc_w2 = (const float*)d_in[4];
    const float* enc_b2 = (const float*)d_in[5];
    const float* g1_w   = (const float*)d_in[6];
    const float* g1_as  = (const float*)d_in[7];
    const float* g1_ad  = (const float*)d_in[8];
    const float* g1_b   = (const float*)d_in[9];
    const float* g2_w   = (const float*)d_in[10];
    const float* g2_as  = (const float*)d_in[11];
    const float* g2_ad  = (const float*)d_in[12];
    const float* g2_b   = (const float*)d_in[13];
    const float* dec_w1 = (const float*)d_in[14];
    const float* dec_b1 = (const float*)d_in[15];
    const float* dec_w2 = (const float*)d_in[16];
    const float* dec_b2 = (const float*)d_in[17];

    const int N = N_NODES, ET = ET_EDGES;

    // workspace layout (floats)
    float* ws   = (float*)d_ws;
    float* henc = ws;                        //  3,200,000
    float* agg  = ws + 3200000;              // 12,800,000
    float* h2   = ws + 16000000;             //  3,200,000
    float* out2 = ws + 19200000;             //  3,200,000
    float* as1  = ws + 22400000;             //    200,000
    float* ad1  = as1 + 200000;
    float* as2  = ad1 + 200000;
    float* ad2  = as2 + 200000;
    float* wsf  = ad2 + 200000;              // 256
    float* wdf  = wsf + 256;                 // 256
    int*   ib      = (int*)(ws + 23201024);
    int*   deg     = ib;                     // 50,001
    int*   rowp    = ib + 50004;             // 50,001
    int*   cursor  = ib + 100008;            // 50,001
    int*   bsum    = ib + 150012;            // 64
    int*   boff    = ib + 150076;            // 64
    int*   csr_src = ib + 150140;            // 850,000

    // CSR build (multi-block scan)
    hipMemsetAsync(deg, 0, (size_t)N * sizeof(int), stream);
    count_kernel<<<(ET + 255) / 256, 256, 0, stream>>>(ei, deg);
    scanA_kernel<<<NBLK, 1024, 0, stream>>>(deg, rowp, bsum);
    scanB_kernel<<<1, 64, 0, stream>>>(bsum, boff, rowp);
    scanC_kernel<<<(N + 255) / 256, 256, 0, stream>>>(rowp, boff, cursor);
    scatter_kernel<<<(ET + 255) / 256, 256, 0, stream>>>(ei, cursor, csr_src);

    // attention-vector fold + encoder (with fused alpha1)
    fold1_kernel<<<1, 256, 0, stream>>>(g1_w, g1_as, g1_ad, wsf, wdf);
    encoder32_kernel<<<(N + 31) / 32, 256, 0, stream>>>(x, enc_w1, enc_b1, enc_w2, enc_b2,
                                                        wsf, wdf, henc, as1, ad1);

    // GAT1: aggregate in henc-domain, then fused GEMM+ELU+GEMM+alpha2
    aggregate1_kernel<<<(N + 3) / 4, 256, 0, stream>>>(rowp, csr_src, as1, ad1, henc, agg);
    gat1_finish_kernel<<<N / 16, 256, 0, stream>>>(agg, g1_w, g1_b, g2_w, g2_as, g2_ad,
                                                   h2, as2, ad2);

    // GAT2
    aggregate2_kernel<<<(N + 3) / 4, 256, 0, stream>>>(rowp, csr_src, as2, ad2, h2, out2);

    decoder32_kernel<<<(N + 31) / 32, 256, 0, stream>>>(out2, g2_b, dec_w1, dec_b1, dec_w2, dec_b2, (float*)d_out);
}

// Round 6
// 399.307 us; speedup vs baseline: 11.2282x; 1.0442x over previous
//
#include <hip/hip_runtime.h>
#include <hip/hip_bf16.h>

#define N_NODES 50000
#define N_EDGES 800000
#define ET_EDGES 850000   // + self loops
#define HEADS 4
#define NBLK 49           // ceil(N_NODES/1024)

__device__ __forceinline__ float lrelu(float v) { return v > 0.f ? v : 0.2f * v; }

__device__ __forceinline__ void edge_sd(const int* __restrict__ ei, int e, int& s, int& d) {
    if (e < N_EDGES) { s = ei[e]; d = ei[N_EDGES + e]; }
    else { s = d = e - N_EDGES; }
}

// ---------------- CSR build ----------------
__global__ __launch_bounds__(256) void count_kernel(const int* __restrict__ ei, int* __restrict__ deg) {
    int e = blockIdx.x * 256 + threadIdx.x;
    if (e >= ET_EDGES) return;
    int s, d; edge_sd(ei, e, s, d);
    atomicAdd(deg + d, 1);
}

// phase A: per-1024-block exclusive scan via wave shuffles (2 barriers)
__global__ __launch_bounds__(1024) void scanA_kernel(const int* __restrict__ deg,
                                                     int* __restrict__ rowp, int* __restrict__ bsum) {
    __shared__ int s_wt[16];
    __shared__ int s_we[16];
    int tid = threadIdx.x;
    int wid = tid >> 6, lane = tid & 63;
    int i = blockIdx.x * 1024 + tid;
    int v = (i < N_NODES) ? deg[i] : 0;
    int x = v;
    #pragma unroll
    for (int off = 1; off < 64; off <<= 1) {
        int t = __shfl_up(x, off);
        if (lane >= off) x += t;
    }
    if (lane == 63) s_wt[wid] = x;
    __syncthreads();
    if (tid < 16) {
        int wv = s_wt[tid];
        int y = wv;
        #pragma unroll
        for (int off = 1; off < 16; off <<= 1) {
            int t = __shfl_up(y, off);
            if (tid >= off) y += t;
        }
        s_we[tid] = y - wv;   // exclusive wave offset
    }
    __syncthreads();
    int excl = x - v + s_we[wid];
    if (i < N_NODES) rowp[i] = excl;
    if (tid == 1023) bsum[blockIdx.x] = excl + v;
}

// phase B: scan the 49 block sums (single wave)
__global__ __launch_bounds__(64) void scanB_kernel(const int* __restrict__ bsum,
                                                   int* __restrict__ boff, int* __restrict__ rowp) {
    int lane = threadIdx.x;
    int v = (lane < NBLK) ? bsum[lane] : 0;
    int x = v;
    #pragma unroll
    for (int off = 1; off < 64; off <<= 1) {
        int t = __shfl_up(x, off);
        if (lane >= off) x += t;
    }
    if (lane < NBLK) boff[lane] = x - v;
    if (lane == NBLK - 1) rowp[N_NODES] = x;
}

__global__ __launch_bounds__(256) void scanC_kernel(int* __restrict__ rowp,
                                                    const int* __restrict__ boff, int* __restrict__ cursor) {
    int i = blockIdx.x * 256 + threadIdx.x;
    if (i >= N_NODES) return;
    int v = rowp[i] + boff[i >> 10];
    rowp[i] = v;
    cursor[i] = v;
}

__global__ __launch_bounds__(256) void scatter_kernel(const int* __restrict__ ei,
                                                      int* __restrict__ cursor, int* __restrict__ csr_src) {
    int e = blockIdx.x * 256 + threadIdx.x;
    if (e >= ET_EDGES) return;
    int s, d; edge_sd(ei, e, s, d);
    int pos = atomicAdd(cursor + d, 1);
    csr_src[pos] = s;
}

// ---------------- fold attention vectors through g1_w ----------------
__global__ __launch_bounds__(256) void fold1_kernel(
    const float* __restrict__ g1w, const float* __restrict__ g1as, const float* __restrict__ g1ad,
    float* __restrict__ wsf, float* __restrict__ wdf) {
    int tid = threadIdx.x;       // tid = h*64+k
    int h = tid >> 6, k = tid & 63;
    float as_acc = 0.f, ad_acc = 0.f;
    #pragma unroll 8
    for (int c = 0; c < 64; ++c) {
        float w = g1w[k * 256 + h * 64 + c];
        as_acc += w * g1as[h * 64 + c];
        ad_acc += w * g1ad[h * 64 + c];
    }
    wsf[tid] = as_acc;
    wdf[tid] = ad_acc;
}

// ---------------- encoder (32 nodes/block) + fused alpha1 ----------------
__global__ __launch_bounds__(256) void encoder32_kernel(
    const float* __restrict__ x, const float* __restrict__ w1, const float* __restrict__ b1,
    const float* __restrict__ w2, const float* __restrict__ b2,
    const float* __restrict__ wsf, const float* __restrict__ wdf,
    float* __restrict__ henc, float* __restrict__ as1, float* __restrict__ ad1) {
    __shared__ float s_w2[4096];     // w2[64][64]
    __shared__ float s_t[32][64];
    __shared__ float s_x[32][8];
    __shared__ float s_he[32][65];   // +1 pad
    __shared__ float s_wf[8 * 65];
    int tid = threadIdx.x;
    int node0 = blockIdx.x * 32;
    for (int i = tid; i < 4096; i += 256) s_w2[i] = w2[i];
    for (int i = tid; i < 224; i += 256) {
        int src = node0 * 7 + i;
        s_x[i / 7][i % 7] = (src < N_NODES * 7) ? x[src] : 0.f;
    }
    for (int i = tid; i < 512; i += 256) {
        int g = i >> 6, k = i & 63;
        int h = g & 3;
        s_wf[g * 65 + k] = (g < 4) ? wsf[h * 64 + k] : wdf[h * 64 + k];
    }
    int c = tid & 63;
    int mg = tid >> 6;
    float w1c[7];
    #pragma unroll
    for (int k = 0; k < 7; ++k) w1c[k] = w1[k * 64 + c];
    float b1c = b1[c];
    __syncthreads();
    #pragma unroll
    for (int m = 0; m < 8; ++m) {
        int nn = mg * 8 + m;
        float a = b1c;
        #pragma unroll
        for (int k = 0; k < 7; ++k) a += s_x[nn][k] * w1c[k];
        s_t[nn][c] = fmaxf(a, 0.f);
    }
    __syncthreads();
    float acc[8];
    float b2c = b2[c];
    #pragma unroll
    for (int m = 0; m < 8; ++m) acc[m] = b2c;
    #pragma unroll 4
    for (int k = 0; k < 64; ++k) {
        float w = s_w2[k * 64 + c];
        #pragma unroll
        for (int m = 0; m < 8; ++m) acc[m] += s_t[mg * 8 + m][k] * w;
    }
    #pragma unroll
    for (int m = 0; m < 8; ++m) {
        int nn = mg * 8 + m;
        int node = node0 + nn;
        s_he[nn][c] = acc[m];
        if (node < N_NODES) henc[node * 64 + c] = acc[m];
    }
    __syncthreads();
    {
        int nn = tid >> 3, r = tid & 7;
        int node = node0 + nn;
        const float* wf = s_wf + r * 65;
        float sum = 0.f;
        #pragma unroll 8
        for (int k = 0; k < 64; ++k) sum += s_he[nn][k] * wf[k];
        if (node < N_NODES) {
            int hh = r & 3;
            if (r < 4) as1[node * 4 + hh] = sum;
            else       ad1[node * 4 + hh] = sum;
        }
    }
}

// ---------------- GAT1 aggregation, single-pass softmax (no max-shift) ----------------
__global__ __launch_bounds__(256) void aggregate1_kernel(
    const int* __restrict__ row, const int* __restrict__ csr_src,
    const float* __restrict__ as, const float* __restrict__ ad,
    const float* __restrict__ henc, float* __restrict__ agg) {
    int wslot = threadIdx.x >> 6;
    int lane  = threadIdx.x & 63;
    int n = blockIdx.x * 4 + wslot;
    __shared__ int    ls[4][64];
    __shared__ float4 lp4[4][64];
    if (n >= N_NODES) return;
    int base = row[n];
    int deg  = row[n + 1] - base;
    float4 add = *(const float4*)(ad + n * 4);

    float4 l = make_float4(0.f, 0.f, 0.f, 0.f);
    float4 acc = make_float4(0.f, 0.f, 0.f, 0.f);
    for (int c0 = 0; c0 < deg; c0 += 64) {
        int j = c0 + lane;
        int s = 0;
        float4 p = make_float4(0.f, 0.f, 0.f, 0.f);
        if (j < deg) {
            s = csr_src[base + j];
            float4 a = *(const float4*)(as + s * 4);
            p.x = __expf(lrelu(a.x + add.x));
            p.y = __expf(lrelu(a.y + add.y));
            p.z = __expf(lrelu(a.z + add.z));
            p.w = __expf(lrelu(a.w + add.w));
        }
        ls[wslot][lane] = s;
        lp4[wslot][lane] = p;
        float4 t = p;
        #pragma unroll
        for (int off = 32; off > 0; off >>= 1) {
            t.x += __shfl_xor(t.x, off);
            t.y += __shfl_xor(t.y, off);
            t.z += __shfl_xor(t.z, off);
            t.w += __shfl_xor(t.w, off);
        }
        l.x += t.x; l.y += t.y; l.z += t.z; l.w += t.w;
        int cnt = min(64, deg - c0);
        const int*    lsw = ls[wslot];
        const float4* lpw = lp4[wslot];
        int j2 = 0;
        for (; j2 + 4 <= cnt; j2 += 4) {
            int a0 = lsw[j2+0] * 64 + lane;
            int a1 = lsw[j2+1] * 64 + lane;
            int a2 = lsw[j2+2] * 64 + lane;
            int a3 = lsw[j2+3] * 64 + lane;
            float v0 = henc[a0], v1 = henc[a1], v2 = henc[a2], v3 = henc[a3];
            float4 p0 = lpw[j2+0], p1 = lpw[j2+1], p2 = lpw[j2+2], p3 = lpw[j2+3];
            acc.x += p0.x*v0 + p1.x*v1 + p2.x*v2 + p3.x*v3;
            acc.y += p0.y*v0 + p1.y*v1 + p2.y*v2 + p3.y*v3;
            acc.z += p0.z*v0 + p1.z*v1 + p2.z*v2 + p3.z*v3;
            acc.w += p0.w*v0 + p1.w*v1 + p2.w*v2 + p3.w*v3;
        }
        for (; j2 < cnt; ++j2) {
            float v = henc[lsw[j2] * 64 + lane];
            float4 pj = lpw[j2];
            acc.x += pj.x * v; acc.y += pj.y * v;
            acc.z += pj.z * v; acc.w += pj.w * v;
        }
    }
    float4 r;
    r.x = acc.x / (l.x + 1e-16f);
    r.y = acc.y / (l.y + 1e-16f);
    r.z = acc.z / (l.z + 1e-16f);
    r.w = acc.w / (l.w + 1e-16f);
    *(float4*)(agg + (size_t)n * 256 + lane * 4) = r;   // agg[n][k*4+h]
}

// ---------------- fused GEMM1+ELU+GEMM2 + alpha2: 32 nodes/block, 36KB LDS reused ----------------
__global__ __launch_bounds__(256, 4) void gat1_finish_kernel(
    const float* __restrict__ agg, const float* __restrict__ g1w, const float* __restrict__ g1b,
    const float* __restrict__ g2w, const float* __restrict__ g2as, const float* __restrict__ g2ad,
    float* __restrict__ h2, float* __restrict__ as2, float* __restrict__ ad2) {
    __shared__ float s_buf[256 * 36];   // 36KB: first s_a1[idx=k*4+h][m], then s_vT[k][m]
    int tid = threadIdx.x;
    int node0 = blockIdx.x * 32;
    // stage agg -> s_a1 (coalesced global; LDS stride 36 writes)
    for (int i = tid; i < 8192; i += 256) {
        int m = i >> 8, idx = i & 255;
        int gi = node0 * 256 + i;
        s_buf[idx * 36 + m] = (gi < N_NODES * 256) ? agg[gi] : 0.f;
    }
    __syncthreads();
    // GEMM1: out1[m][q] = sum_k a1[(k*4+h)][m] * g1w[k*256+q],  h = q>>6 (wave-uniform)
    int q = tid;
    int h = q >> 6;
    float acc1[32];
    #pragma unroll
    for (int m = 0; m < 32; ++m) acc1[m] = 0.f;
    const float* wp = g1w + q;
    #pragma unroll 8
    for (int k = 0; k < 64; ++k) {
        float w = wp[k * 256];
        const float* a = s_buf + (k * 4 + h) * 36;
        #pragma unroll
        for (int g = 0; g < 8; ++g) {
            float4 av = *(const float4*)(a + g * 4);
            acc1[g * 4 + 0] += av.x * w;
            acc1[g * 4 + 1] += av.y * w;
            acc1[g * 4 + 2] += av.z * w;
            acc1[g * 4 + 3] += av.w * w;
        }
    }
    float bias = g1b[q];
    __syncthreads();   // all s_a1 reads done; reuse buffer as s_vT[k=q][m]
    #pragma unroll
    for (int m = 0; m < 32; ++m) {
        float v = acc1[m] + bias;
        s_buf[q * 36 + m] = v > 0.f ? v : expm1f(v);   // ELU
    }
    __syncthreads();
    // GEMM2: h2[m][c] = sum_k vT[k][m] * g2w[k*64+c]; wave wv owns m = wv*8..+7
    int c = tid & 63;
    int wv = tid >> 6;
    int m0 = wv * 8;
    float acc2[8] = {0.f, 0.f, 0.f, 0.f, 0.f, 0.f, 0.f, 0.f};
    const float* w2p = g2w + c;
    #pragma unroll 8
    for (int k = 0; k < 256; ++k) {
        float w = w2p[k * 64];
        const float* vp = s_buf + k * 36 + m0;
        float4 v0 = *(const float4*)(vp);
        float4 v1 = *(const float4*)(vp + 4);
        acc2[0] += v0.x * w; acc2[1] += v0.y * w;
        acc2[2] += v0.z * w; acc2[3] += v0.w * w;
        acc2[4] += v1.x * w; acc2[5] += v1.y * w;
        acc2[6] += v1.z * w; acc2[7] += v1.w * w;
    }
    // write h2 + fused alpha2 (16-lane shuffle reduce; g2as/ad flat index == c)
    float ga = g2as[c], gd = g2ad[c];
    int kk = c & 15;
    #pragma unroll
    for (int mm = 0; mm < 8; ++mm) {
        int n = node0 + m0 + mm;
        if (n < N_NODES) h2[(size_t)n * 64 + c] = acc2[mm];
        float vs = acc2[mm] * ga;
        float vd = acc2[mm] * gd;
        #pragma unroll
        for (int off = 8; off > 0; off >>= 1) {
            vs += __shfl_xor(vs, off);
            vd += __shfl_xor(vd, off);
        }
        if (kk == 0 && n < N_NODES) {
            as2[n * 4 + (c >> 4)] = vs;
            ad2[n * 4 + (c >> 4)] = vd;
        }
    }
}

// ---------------- GAT2 aggregate, single-pass softmax ----------------
__global__ __launch_bounds__(256) void aggregate2_kernel(
    const int* __restrict__ row, const int* __restrict__ csr_src,
    const float* __restrict__ as, const float* __restrict__ ad,
    const float* __restrict__ h, float* __restrict__ out) {
    int wslot = threadIdx.x >> 6;
    int lane  = threadIdx.x & 63;
    int n = blockIdx.x * 4 + wslot;
    __shared__ int    ls[4][64];
    __shared__ float4 lp4[4][64];
    if (n >= N_NODES) return;
    int base = row[n];
    int deg  = row[n + 1] - base;
    int head = lane >> 4;
    float4 add = *(const float4*)(ad + n * 4);

    float4 l = make_float4(0.f, 0.f, 0.f, 0.f);
    float acc = 0.f;
    for (int c0 = 0; c0 < deg; c0 += 64) {
        int j = c0 + lane;
        int s = 0;
        float4 p = make_float4(0.f, 0.f, 0.f, 0.f);
        if (j < deg) {
            s = csr_src[base + j];
            float4 a = *(const float4*)(as + s * 4);
            p.x = __expf(lrelu(a.x + add.x));
            p.y = __expf(lrelu(a.y + add.y));
            p.z = __expf(lrelu(a.z + add.z));
            p.w = __expf(lrelu(a.w + add.w));
        }
        ls[wslot][lane] = s;
        lp4[wslot][lane] = p;
        float4 t = p;
        #pragma unroll
        for (int off = 32; off > 0; off >>= 1) {
            t.x += __shfl_xor(t.x, off);
            t.y += __shfl_xor(t.y, off);
            t.z += __shfl_xor(t.z, off);
            t.w += __shfl_xor(t.w, off);
        }
        l.x += t.x; l.y += t.y; l.z += t.z; l.w += t.w;
        int cnt = min(64, deg - c0);
        const int*   lsw = ls[wslot];
        const float* lpf = (const float*)lp4[wslot];
        int j2 = 0;
        for (; j2 + 4 <= cnt; j2 += 4) {
            int a0 = lsw[j2+0] * 64 + lane;
            int a1 = lsw[j2+1] * 64 + lane;
            int a2 = lsw[j2+2] * 64 + lane;
            int a3 = lsw[j2+3] * 64 + lane;
            float v0 = h[a0], v1 = h[a1], v2 = h[a2], v3 = h[a3];
            float p0 = lpf[(j2+0) * 4 + head];
            float p1 = lpf[(j2+1) * 4 + head];
            float p2 = lpf[(j2+2) * 4 + head];
            float p3 = lpf[(j2+3) * 4 + head];
            acc += p0*v0 + p1*v1 + p2*v2 + p3*v3;
        }
        for (; j2 < cnt; ++j2) {
            acc += lpf[j2 * 4 + head] * h[lsw[j2] * 64 + lane];
        }
    }
    float lh = (head == 0) ? l.x : (head == 1) ? l.y : (head == 2) ? l.z : l.w;
    out[(size_t)n * 64 + lane] = acc / (lh + 1e-16f);
}

// ---------------- decoder: 32 nodes/block, w1 in LDS ----------------
__global__ __launch_bounds__(256) void decoder32_kernel(
    const float* __restrict__ hin, const float* __restrict__ gb,
    const float* __restrict__ w1, const float* __restrict__ b1,
    const float* __restrict__ w2, const float* __restrict__ b2, float* __restrict__ out) {
    __shared__ float s_w1[4096];
    __shared__ float s_w2[256];
    __shared__ float s_h[32][64];
    __shared__ float s_t[32][64];
    int tid = threadIdx.x;
    int node0 = blockIdx.x * 32;
    for (int i = tid; i < 4096; i += 256) s_w1[i] = w1[i];
    if (tid < 256) s_w2[tid] = w2[tid];
    for (int i = tid; i < 2048; i += 256) {
        int nn = i >> 6, k = i & 63;
        int node = node0 + nn;
        s_h[nn][k] = (node < N_NODES ? hin[(size_t)node * 64 + k] : 0.f) + gb[k];
    }
    __syncthreads();
    int c = tid & 63;
    int mg = tid >> 6;
    float b1c = b1[c];
    float acc[8];
    #pragma unroll
    for (int m = 0; m < 8; ++m) acc[m] = b1c;
    #pragma unroll 4
    for (int k = 0; k < 64; ++k) {
        float w = s_w1[k * 64 + c];
        #pragma unroll
        for (int m = 0; m < 8; ++m) acc[m] += s_h[mg * 8 + m][k] * w;
    }
    #pragma unroll
    for (int m = 0; m < 8; ++m) s_t[mg * 8 + m][c] = fmaxf(acc[m], 0.f);
    __syncthreads();
    if (tid < 128) {
        int m = tid >> 2, j = tid & 3;
        int node = node0 + m;
        if (node < N_NODES) {
            float a = b2[j];
            #pragma unroll 16
            for (int k = 0; k < 64; ++k) a += s_t[m][k] * s_w2[k * 4 + j];
            out[node * 4 + j] = a;
        }
    }
}

extern "C" void kernel_launch(void* const* d_in, const int* in_sizes, int n_in,
                              void* d_out, int out_size, void* d_ws, size_t ws_size,
                              hipStream_t stream) {
    const float* x      = (const float*)d_in[0];
    const int*   ei     = (const int*)d_in[1];
    const float* enc_w1 = (const float*)d_in[2];
    const float* enc_b1 = (const float*)d_in[3];
    const float* enc_w2 = (const float*)d_in[4];
    const float* enc_b2 = (const float*)d_in[5];
    const float* g1_w   = (const float*)d_in[6];
    const float* g1_as  = (const float*)d_in[7];
    const float* g1_ad  = (const float*)d_in[8];
    const float* g1_b   = (const float*)d_in[9];
    const float* g2_w   = (const float*)d_in[10];
    const float* g2_as  = (const float*)d_in[11];
    const float* g2_ad  = (const float*)d_in[12];
    const float* g2_b   = (const float*)d_in[13];
    const float* dec_w1 = (const float*)d_in[14];
    const float* dec_b1 = (const float*)d_in[15];
    const float* dec_w2 = (const float*)d_in[16];
    const float* dec_b2 = (const float*)d_in[17];

    const int N = N_NODES, ET = ET_EDGES;

    // workspace layout (floats)
    float* ws   = (float*)d_ws;
    float* henc = ws;                        //  3,200,000
    float* agg  = ws + 3200000;              // 12,800,000
    float* h2   = ws + 16000000;             //  3,200,000
    float* out2 = ws + 19200000;             //  3,200,000
    float* as1  = ws + 22400000;             //    200,000
    float* ad1  = as1 + 200000;
    float* as2  = ad1 + 200000;
    float* ad2  = as2 + 200000;
    float* wsf  = ad2 + 200000;              // 256
    float* wdf  = wsf + 256;                 // 256
    int*   ib      = (int*)(ws + 23201024);
    int*   deg     = ib;                     // 50,001
    int*   rowp    = ib + 50004;             // 50,001
    int*   cursor  = ib + 100008;            // 50,001
    int*   bsum    = ib + 150012;            // 64
    int*   boff    = ib + 150076;            // 64
    int*   csr_src = ib + 150140;            // 850,000

    // CSR build (wave-shuffle multi-block scan)
    hipMemsetAsync(deg, 0, (size_t)N * sizeof(int), stream);
    count_kernel<<<(ET + 255) / 256, 256, 0, stream>>>(ei, deg);
    scanA_kernel<<<NBLK, 1024, 0, stream>>>(deg, rowp, bsum);
    scanB_kernel<<<1, 64, 0, stream>>>(bsum, boff, rowp);
    scanC_kernel<<<(N + 255) / 256, 256, 0, stream>>>(rowp, boff, cursor);
    scatter_kernel<<<(ET + 255) / 256, 256, 0, stream>>>(ei, cursor, csr_src);

    // attention-vector fold + encoder (with fused alpha1)
    fold1_kernel<<<1, 256, 0, stream>>>(g1_w, g1_as, g1_ad, wsf, wdf);
    encoder32_kernel<<<(N + 31) / 32, 256, 0, stream>>>(x, enc_w1, enc_b1, enc_w2, enc_b2,
                                                        wsf, wdf, henc, as1, ad1);

    // GAT1: aggregate in henc-domain, then fused GEMM+ELU+GEMM+alpha2
    aggregate1_kernel<<<(N + 3) / 4, 256, 0, stream>>>(rowp, csr_src, as1, ad1, henc, agg);
    gat1_finish_kernel<<<(N + 31) / 32, 256, 0, stream>>>(agg, g1_w, g1_b, g2_w, g2_as, g2_ad,
                                                          h2, as2, ad2);

    // GAT2
    aggregate2_kernel<<<(N + 3) / 4, 256, 0, stream>>>(rowp, csr_src, as2, ad2, h2, out2);

    decoder32_kernel<<<(N + 31) / 32, 256, 0, stream>>>(out2, g2_b, dec_w1, dec_b1, dec_w2, dec_b2, (float*)d_out);
}